// Round 3
// baseline (7401.175 us; speedup 1.0000x reference)
//
#include <hip/hip_runtime.h>
#include <hip/hip_bf16.h>
#include <math.h>

#define Bb   128
#define Ss   512
#define Ff   64
#define Hh   512
#define NGc  2053          // 4*H + 5
#define Kk   576           // F + H
#define NWG  32
#define NT   80            // padded gate cols per WG (64 gates + 5 d + pad)
#define BST  584           // padded k-stride (shorts) for LDS weights

// workspace layout (bytes)
#define OFF_ARR   0                        // 32 x 128B arrival flags
#define OFF_HB    4096                     // 2 x B*H bf16 ping-pong (131072 each)
#define OFF_HFIN  266240                   // B*H fp32
#define OFF_CFIN  528384                   // 5 x B*H fp32
#define OFF_R1    1839104                  // 128x256 fp32
#define OFF_R2    1970176                  // 128x128 fp32
#define OFF_Y1    2035712                  // 5 x 128x256 fp32

typedef __attribute__((ext_vector_type(8))) short short8;
typedef __attribute__((ext_vector_type(4))) float f32x4;

__device__ __forceinline__ unsigned short f2bf(float f) {
    union { float f; unsigned u; } v; v.f = f;
    unsigned r = v.u + 0x7fffu + ((v.u >> 16) & 1u);
    return (unsigned short)(r >> 16);
}

// ---- fence-free barrier: all shared traffic is relaxed agent-scope (LLC),
// ---- so NO buffer_wbl2 / buffer_inv is ever needed ----
__device__ __forceinline__ void bar_arrive(unsigned* arr, int wg, unsigned val) {
    __syncthreads();                 // compiler drains vmcnt before s_barrier:
                                     // all waves' h-stores (LLC write-through) done
    if (threadIdx.x == 0) {
        __hip_atomic_store(&arr[wg * 32], val, __ATOMIC_RELAXED, __HIP_MEMORY_SCOPE_AGENT);
    }
}

__device__ __forceinline__ void bar_wait(unsigned* arr, unsigned tgt) {
    if (threadIdx.x < 64) {
        const int  l    = threadIdx.x;
        const bool mine = l < NWG;
        for (;;) {
            unsigned v = mine ? __hip_atomic_load(&arr[l * 32], __ATOMIC_RELAXED,
                                                  __HIP_MEMORY_SCOPE_AGENT)
                              : 0xFFFFFFFFu;
            if (__all((int)(v >= tgt))) break;
            __builtin_amdgcn_s_sleep(1);
        }
    }
    __syncthreads();
}

__global__ __launch_bounds__(256, 1) void mclstm_main(
    const float* __restrict__ xin, const float* __restrict__ Wm,
    const float* __restrict__ Um,  const float* __restrict__ k1,
    const float* __restrict__ bias, const float* __restrict__ bias1,
    float* __restrict__ out, unsigned char* __restrict__ ws)
{
    __shared__ __align__(16) short sB[NT * BST];   // 91 KB: Bt[n][k] bf16
    __shared__ float sD[128 * 8];                  // d-gate dump / d values

    const int tid  = threadIdx.x;
    const int wg   = blockIdx.x;
    const int lane = tid & 63;
    const int wave = tid >> 6;
    const int j0   = wg * 16;

    unsigned* arr  = (unsigned*)(ws + OFF_ARR);
    short*    hbuf = (short*)(ws + OFF_HB);
    float*    hfin = (float*)(ws + OFF_HFIN);
    float*    cfin = (float*)(ws + OFF_CFIN);

    // ---- stage weights into LDS: sB[n*BST + k], n in [0,80) ----
    for (int e = tid; e < NT * Kk; e += 256) {
        int n = e % NT, k = e / NT;
        int col = -1;
        if (n < 64)      col = (n >> 4) * Hh + j0 + (n & 15);
        else if (n < 69) col = 4 * Hh + (n - 64);
        float v = 0.f;
        if (col >= 0) v = (k < Ff) ? Wm[(size_t)k * NGc + col]
                                   : Um[(size_t)(k - Ff) * NGc + col];
        sB[n * BST + k] = (short)f2bf(v);
    }

    const int col16 = lane & 15;
    const int quad  = lane >> 4;
    const int kgrp  = quad * 8;

    // bias per n-tile (col = col16)
    float biasreg[5];
#pragma unroll
    for (int nt = 0; nt < 5; ++nt) {
        int col;
        if (nt < 4) col = nt * Hh + j0 + col16;
        else        col = (col16 < 5) ? (4 * Hh + col16) : -1;
        biasreg[nt] = (col >= 0) ? bias[col] : 0.f;
    }

    // per-lane elementwise constants: lane owns hidden unit u = col16
    const float s1v = bias1[j0 + col16];
    const float s2v = bias1[Hh + j0 + col16];
    float kv[5];
#pragma unroll
    for (int g = 0; g < 5; ++g) kv[g] = k1[g * Hh + j0 + col16];
    float cp[2][4] = {{0,0,0,0},{0,0,0,0}};     // c-state for lane's 8 rows

    const int row0 = wave * 32 + col16;         // m-tile 0 row (A-frag)
    const int row1 = wave * 32 + 16 + col16;    // m-tile 1 row

    __syncthreads();

    for (int t = 0; t < Ss; ++t) {
        const short* hcur  = hbuf + (size_t)(t & 1) * (Bb * Hh);
        short*       hnext = hbuf + (size_t)((t + 1) & 1) * (Bb * Hh);

        // ---- accumulators (bias-init) ----
        f32x4 acc[5][2];
#pragma unroll
        for (int nt = 0; nt < 5; ++nt)
#pragma unroll
            for (int mt = 0; mt < 2; ++mt) {
                f32x4 z = {biasreg[nt], biasreg[nt], biasreg[nt], biasreg[nt]};
                acc[nt][mt] = z;
            }

        // ---- x_t loads + x@W MFMAs BEFORE the barrier (off critical path) ----
        short8 Ax[2][2];
#pragma unroll
        for (int k0 = 0; k0 < 2; ++k0) {
            int kb = k0 * 32 + kgrp;
            const float* p0 = xin + ((size_t)row0 * Ss + t) * Ff + kb;
            const float* p1 = xin + ((size_t)row1 * Ss + t) * Ff + kb;
            f32x4 f00 = *(const f32x4*)(p0);
            f32x4 f01 = *(const f32x4*)(p0 + 4);
            f32x4 f10 = *(const f32x4*)(p1);
            f32x4 f11 = *(const f32x4*)(p1 + 4);
#pragma unroll
            for (int j = 0; j < 4; ++j) {
                Ax[k0][0][j]     = (short)f2bf(f00[j]); Ax[k0][0][4 + j] = (short)f2bf(f01[j]);
                Ax[k0][1][j]     = (short)f2bf(f10[j]); Ax[k0][1][4 + j] = (short)f2bf(f11[j]);
            }
        }
#pragma unroll
        for (int k0 = 0; k0 < 2; ++k0) {
            int kb = k0 * 32 + kgrp;
#pragma unroll
            for (int nt = 0; nt < 5; ++nt) {
                short8 b = *(const short8*)(sB + (nt * 16 + col16) * BST + kb);
                acc[nt][0] = __builtin_amdgcn_mfma_f32_16x16x32_bf16(Ax[k0][0], b, acc[nt][0], 0, 0, 0);
                acc[nt][1] = __builtin_amdgcn_mfma_f32_16x16x32_bf16(Ax[k0][1], b, acc[nt][1], 0, 0, 0);
            }
        }

        // ---- wait for step-t h to be LLC-visible ----
        bar_wait(arr, (unsigned)t);

        // ---- h loads: relaxed agent-scope 8B atomics (LLC-direct, no stale L2) ----
        short8 Ah[16][2];
#pragma unroll
        for (int k0 = 0; k0 < 16; ++k0) {
            int kb = k0 * 32 + kgrp;
            const unsigned long long* p0 = (const unsigned long long*)(hcur + (size_t)row0 * Hh + kb);
            const unsigned long long* p1 = (const unsigned long long*)(hcur + (size_t)row1 * Hh + kb);
            union { unsigned long long q[2]; short8 s; } u0, u1;
            u0.q[0] = __hip_atomic_load(p0,     __ATOMIC_RELAXED, __HIP_MEMORY_SCOPE_AGENT);
            u0.q[1] = __hip_atomic_load(p0 + 1, __ATOMIC_RELAXED, __HIP_MEMORY_SCOPE_AGENT);
            u1.q[0] = __hip_atomic_load(p1,     __ATOMIC_RELAXED, __HIP_MEMORY_SCOPE_AGENT);
            u1.q[1] = __hip_atomic_load(p1 + 1, __ATOMIC_RELAXED, __HIP_MEMORY_SCOPE_AGENT);
            Ah[k0][0] = u0.s; Ah[k0][1] = u1.s;
        }

        // ---- h part (k = 64..575) ----
#pragma unroll
        for (int k0 = 0; k0 < 16; ++k0) {
            int kb = 64 + k0 * 32 + kgrp;
#pragma unroll
            for (int nt = 0; nt < 5; ++nt) {
                short8 b = *(const short8*)(sB + (nt * 16 + col16) * BST + kb);
                acc[nt][0] = __builtin_amdgcn_mfma_f32_16x16x32_bf16(Ah[k0][0], b, acc[nt][0], 0, 0, 0);
                acc[nt][1] = __builtin_amdgcn_mfma_f32_16x16x32_bf16(Ah[k0][1], b, acc[nt][1], 0, 0, 0);
            }
        }

        // ---- d gate: dump cols 0..4 (tile 4), softmax(tanh(.)) per row ----
        if (col16 < 5) {
#pragma unroll
            for (int mt = 0; mt < 2; ++mt)
#pragma unroll
                for (int j = 0; j < 4; ++j)
                    sD[(wave * 32 + mt * 16 + quad * 4 + j) * 8 + col16] = acc[4][mt][j];
        }
        __syncthreads();
        if (tid < 128) {
            int r = tid;
            float v[5], mx = -1e30f;
#pragma unroll
            for (int c = 0; c < 5; ++c) { v[c] = tanhf(sD[r * 8 + c]); mx = fmaxf(mx, v[c]); }
            float s = 0.f;
#pragma unroll
            for (int c = 0; c < 5; ++c) { v[c] = __expf(v[c] - mx); s += v[c]; }
            float inv = 1.f / s;
#pragma unroll
            for (int c = 0; c < 5; ++c) sD[r * 8 + c] = v[c] * inv;
            if (t == Ss - 1 && wg == 0) {
#pragma unroll
                for (int c = 0; c < 5; ++c) out[1408 + r * 5 + c] = v[c] * inv;
            }
        }
        __syncthreads();

        // ---- cell update: i/f/g/o are tiles 0..3, same lane, no shuffles ----
#pragma unroll
        for (int mt = 0; mt < 2; ++mt) {
#pragma unroll
            for (int j = 0; j < 4; ++j) {
                int r = wave * 32 + mt * 16 + quad * 4 + j;
                float i_ = 1.f / (1.f + __expf(-acc[0][mt][j]));
                float f_ = 1.f / (1.f + __expf(-acc[1][mt][j]));
                float g_ = tanhf(acc[2][mt][j]);
                float o_ = 1.f / (1.f + __expf(-acc[3][mt][j]));
                float c1v = tanhf(g_);
                float c5v = cp[mt][j];
                float c3v = f_ * c5v + i_ * g_;
                float c2v = s2v * c3v + (1.f - s2v) * c1v;
                float c4v = s1v * c3v + (1.f - s1v) * c5v;
                const float* dr = sD + r * 8;
                float cn = dr[0] * kv[0] * c1v + dr[1] * kv[1] * c2v + dr[2] * kv[2] * c3v
                         + dr[3] * kv[3] * c4v + dr[4] * kv[4] * c5v;
                float hn = o_ * tanhf(cn);
                cp[mt][j] = cn;
                size_t off = (size_t)r * Hh + j0 + col16;
                // LLC write-through store (agent relaxed): no fence needed later
                __hip_atomic_store((unsigned short*)&hnext[off], f2bf(hn),
                                   __ATOMIC_RELAXED, __HIP_MEMORY_SCOPE_AGENT);
                if (t == Ss - 1) {
                    float hnf = hn;
                    hfin[off] = hnf;
                    cfin[0 * Bb * Hh + off] = c1v;
                    cfin[1 * Bb * Hh + off] = c2v;
                    cfin[2 * Bb * Hh + off] = c3v;
                    cfin[3 * Bb * Hh + off] = c4v;
                    cfin[4 * Bb * Hh + off] = c5v;
                }
            }
        }
        if (t < Ss - 1) bar_arrive(arr, wg, (unsigned)(t + 1));
    }
}

// ---- heads: stage A: r1 = relu(h@rw1+rb1); y1[hd] = relu(c_hd@dw1+db1) ----
__global__ __launch_bounds__(256) void stageA(const unsigned char* __restrict__ ws,
    const float* __restrict__ rw1, const float* __restrict__ rb1,
    const float* __restrict__ dw1, const float* __restrict__ db1)
{
    __shared__ float sW[512 * 17];
    const int tid = threadIdx.x;
    const int blk = blockIdx.x;
    const float* hfin = (const float*)(ws + OFF_HFIN);
    const float* cfin = (const float*)(ws + OFF_CFIN);
    float* r1 = (float*)(ws + OFF_R1);
    float* y1 = (float*)(ws + OFF_Y1);

    const float* src; const float* Wm; const float* bv; float* dst; int cblk;
    if (blk < 16) { src = hfin; Wm = rw1; bv = rb1; dst = r1; cblk = blk; }
    else {
        int hd = (blk - 16) >> 4; cblk = (blk - 16) & 15;
        src = cfin + (size_t)hd * Bb * Hh; Wm = dw1; bv = db1;
        dst = y1 + (size_t)hd * Bb * 256;
    }
    for (int e = tid; e < 512 * 16; e += 256) {
        int k = e >> 4, c = e & 15;
        sW[k * 17 + c] = Wm[(size_t)k * 256 + cblk * 16 + c];
    }
    __syncthreads();
    for (int e = tid; e < 128 * 16; e += 256) {
        int r = e >> 4, c = e & 15;
        float a = bv[cblk * 16 + c];
        const float* sp = src + (size_t)r * 512;
        for (int k = 0; k < 512; k += 4) {
            f32x4 h4 = *(const f32x4*)(sp + k);
            a += h4[0] * sW[(k + 0) * 17 + c] + h4[1] * sW[(k + 1) * 17 + c]
               + h4[2] * sW[(k + 2) * 17 + c] + h4[3] * sW[(k + 3) * 17 + c];
        }
        dst[(size_t)r * 256 + cblk * 16 + c] = fmaxf(a, 0.f);
    }
}

// ---- stage B: r2 = relu(r1@rw2+rb2) ----
__global__ __launch_bounds__(256) void stageB(const unsigned char* __restrict__ ws,
    const float* __restrict__ rw2, const float* __restrict__ rb2)
{
    __shared__ float sW[256 * 17];
    const int tid = threadIdx.x;
    const int cblk = blockIdx.x;
    const float* r1 = (const float*)(ws + OFF_R1);
    float* r2 = (float*)(ws + OFF_R2);
    for (int e = tid; e < 256 * 16; e += 256) {
        int k = e >> 4, c = e & 15;
        sW[k * 17 + c] = rw2[(size_t)k * 128 + cblk * 16 + c];
    }
    __syncthreads();
    for (int e = tid; e < 128 * 16; e += 256) {
        int r = e >> 4, c = e & 15;
        float a = rb2[cblk * 16 + c];
        const float* sp = r1 + (size_t)r * 256;
        for (int k = 0; k < 256; k += 4) {
            f32x4 h4 = *(const f32x4*)(sp + k);
            a += h4[0] * sW[(k + 0) * 17 + c] + h4[1] * sW[(k + 1) * 17 + c]
               + h4[2] * sW[(k + 2) * 17 + c] + h4[3] * sW[(k + 3) * 17 + c];
        }
        r2[(size_t)r * 128 + cblk * 16 + c] = fmaxf(a, 0.f);
    }
}

// ---- stage C: BN + final projections + log_softmax ----
__global__ __launch_bounds__(256) void stageC(const unsigned char* __restrict__ ws,
    const float* __restrict__ rbng, const float* __restrict__ rbnb,
    const float* __restrict__ rw3,  const float* __restrict__ rb3,
    const float* __restrict__ dbng, const float* __restrict__ dbnb,
    const float* __restrict__ dw2,  const float* __restrict__ db2,
    float* __restrict__ out)
{
    __shared__ float sc[256], sh[256];
    const int tid = threadIdx.x;
    const int blk = blockIdx.x;
    const float* r2 = (const float*)(ws + OFF_R2);
    const float* y1 = (const float*)(ws + OFF_Y1);
    if (blk == 0) {
        if (tid < 128) {
            int c = tid; float s = 0.f, s2 = 0.f;
            for (int r = 0; r < 128; ++r) { float x = r2[r * 128 + c]; s += x; s2 += x * x; }
            float m = s * (1.f / 128.f), v = s2 * (1.f / 128.f) - m * m;
            float sca = rbng[c] * rsqrtf(v + 1e-5f);
            sc[c] = sca; sh[c] = rbnb[c] - m * sca;
        }
        __syncthreads();
        if (tid < 128) {
            int r = tid; float a = rb3[0];
            for (int c = 0; c < 128; ++c)
                a += (r2[r * 128 + c] * sc[c] + sh[c]) * rw3[c];
            out[r] = a;
        }
    } else {
        int hd = blk - 1;
        const float* y = y1 + (size_t)hd * 128 * 256;
        {
            int c = tid; float s = 0.f, s2 = 0.f;
            for (int r = 0; r < 128; ++r) { float x = y[r * 256 + c]; s += x; s2 += x * x; }
            float m = s * (1.f / 128.f), v = s2 * (1.f / 128.f) - m * m;
            float sca = dbng[c] * rsqrtf(v + 1e-5f);
            sc[c] = sca; sh[c] = dbnb[c] - m * sca;
        }
        __syncthreads();
        if (tid < 128) {
            int r = tid;
            float z0 = db2[0], z1 = db2[1];
            for (int c = 0; c < 256; ++c) {
                float yn = y[r * 256 + c] * sc[c] + sh[c];
                z0 += yn * dw2[c * 2 + 0];
                z1 += yn * dw2[c * 2 + 1];
            }
            float mx = fmaxf(z0, z1);
            float ls = mx + logf(__expf(z0 - mx) + __expf(z1 - mx));
            out[128 + hd * 256 + r * 2 + 0] = z0 - ls;
            out[128 + hd * 256 + r * 2 + 1] = z1 - ls;
        }
    }
}

extern "C" void kernel_launch(void* const* d_in, const int* in_sizes, int n_in,
                              void* d_out, int out_size, void* d_ws, size_t ws_size,
                              hipStream_t stream) {
    const float* x    = (const float*)d_in[0];
    const float* Wm   = (const float*)d_in[1];
    const float* Um   = (const float*)d_in[2];
    const float* k1   = (const float*)d_in[3];
    const float* bias = (const float*)d_in[4];
    const float* b1   = (const float*)d_in[5];
    const float* rw1  = (const float*)d_in[6];
    const float* rb1  = (const float*)d_in[7];
    const float* rw2  = (const float*)d_in[8];
    const float* rb2  = (const float*)d_in[9];
    const float* rbng = (const float*)d_in[10];
    const float* rbnb = (const float*)d_in[11];
    const float* rw3  = (const float*)d_in[12];
    const float* rb3  = (const float*)d_in[13];
    const float* dw1  = (const float*)d_in[14];
    const float* db1  = (const float*)d_in[15];
    const float* dbng = (const float*)d_in[16];
    const float* dbnb = (const float*)d_in[17];
    const float* dw2  = (const float*)d_in[18];
    const float* db2  = (const float*)d_in[19];
    (void)in_sizes; (void)n_in; (void)out_size; (void)ws_size;

    // zero arrival flags + h ping buffer 0
    hipMemsetAsync(d_ws, 0, OFF_HB + Bb * Hh * 2, stream);

    mclstm_main<<<NWG, 256, 0, stream>>>(x, Wm, Um, k1, bias, b1,
                                         (float*)d_out, (unsigned char*)d_ws);
    stageA<<<96, 256, 0, stream>>>((const unsigned char*)d_ws, rw1, rb1, dw1, db1);
    stageB<<<8, 256, 0, stream>>>((const unsigned char*)d_ws, rw2, rb2);
    stageC<<<6, 256, 0, stream>>>((const unsigned char*)d_ws, rbng, rbnb, rw3, rb3,
                                  dbng, dbnb, dw2, db2, (float*)d_out);
}

// Round 5
// 6364.616 us; speedup vs baseline: 1.1629x; 1.1629x over previous
//
#include <hip/hip_runtime.h>
#include <hip/hip_bf16.h>
#include <math.h>

#define Bb   128
#define Ss   512
#define Ff   64
#define Hh   512
#define NGc  2053          // 4*H + 5
#define Kk   576           // F + H
#define NWG  32
#define NT   80            // padded gate cols per WG (64 gates + 5 d + pad)
#define BST  584           // padded k-stride (shorts) for LDS weights
#define SHP  24            // sH row pitch (shorts): 48B keeps 16B alignment, spreads banks

// workspace layout (bytes)
#define OFF_ARR   0                        // 32 x 128B arrival flags
#define OFF_HB    4096                     // 2 x B*H bf16 ping-pong (131072 each)
#define OFF_HFIN  266240                   // B*H fp32
#define OFF_CFIN  528384                   // 5 x B*H fp32
#define OFF_R1    1839104                  // 128x256 fp32
#define OFF_R2    1970176                  // 128x128 fp32
#define OFF_Y1    2035712                  // 5 x 128x256 fp32

typedef __attribute__((ext_vector_type(8))) short short8;
typedef __attribute__((ext_vector_type(4))) float f32x4;
typedef __attribute__((ext_vector_type(4))) int   i32x4a;

__device__ __forceinline__ unsigned short f2bf(float f) {
    union { float f; unsigned u; } v; v.f = f;
    unsigned r = v.u + 0x7fffu + ((v.u >> 16) & 1u);
    return (unsigned short)(r >> 16);
}

// 32 coalescing, L1+L2-bypassing (sc0 sc1 -> LLC coherence point) 16B loads,
// fully pipelined, single drain. Ends with vmcnt(0) so the compiler's
// waitcnt accounting stays conservative-correct after the asm block.
#define HLOAD32(R0, R1, a0, a1)                                        \
  asm volatile(                                                        \
    "global_load_dwordx4 %0, %32, off sc0 sc1\n\t"                     \
    "global_load_dwordx4 %1, %32, off offset:64 sc0 sc1\n\t"           \
    "global_load_dwordx4 %2, %32, off offset:128 sc0 sc1\n\t"          \
    "global_load_dwordx4 %3, %32, off offset:192 sc0 sc1\n\t"          \
    "global_load_dwordx4 %4, %32, off offset:256 sc0 sc1\n\t"          \
    "global_load_dwordx4 %5, %32, off offset:320 sc0 sc1\n\t"          \
    "global_load_dwordx4 %6, %32, off offset:384 sc0 sc1\n\t"          \
    "global_load_dwordx4 %7, %32, off offset:448 sc0 sc1\n\t"          \
    "global_load_dwordx4 %8, %32, off offset:512 sc0 sc1\n\t"          \
    "global_load_dwordx4 %9, %32, off offset:576 sc0 sc1\n\t"          \
    "global_load_dwordx4 %10, %32, off offset:640 sc0 sc1\n\t"         \
    "global_load_dwordx4 %11, %32, off offset:704 sc0 sc1\n\t"         \
    "global_load_dwordx4 %12, %32, off offset:768 sc0 sc1\n\t"         \
    "global_load_dwordx4 %13, %32, off offset:832 sc0 sc1\n\t"         \
    "global_load_dwordx4 %14, %32, off offset:896 sc0 sc1\n\t"         \
    "global_load_dwordx4 %15, %32, off offset:960 sc0 sc1\n\t"         \
    "global_load_dwordx4 %16, %33, off sc0 sc1\n\t"                    \
    "global_load_dwordx4 %17, %33, off offset:64 sc0 sc1\n\t"          \
    "global_load_dwordx4 %18, %33, off offset:128 sc0 sc1\n\t"         \
    "global_load_dwordx4 %19, %33, off offset:192 sc0 sc1\n\t"         \
    "global_load_dwordx4 %20, %33, off offset:256 sc0 sc1\n\t"         \
    "global_load_dwordx4 %21, %33, off offset:320 sc0 sc1\n\t"         \
    "global_load_dwordx4 %22, %33, off offset:384 sc0 sc1\n\t"         \
    "global_load_dwordx4 %23, %33, off offset:448 sc0 sc1\n\t"         \
    "global_load_dwordx4 %24, %33, off offset:512 sc0 sc1\n\t"         \
    "global_load_dwordx4 %25, %33, off offset:576 sc0 sc1\n\t"         \
    "global_load_dwordx4 %26, %33, off offset:640 sc0 sc1\n\t"         \
    "global_load_dwordx4 %27, %33, off offset:704 sc0 sc1\n\t"         \
    "global_load_dwordx4 %28, %33, off offset:768 sc0 sc1\n\t"         \
    "global_load_dwordx4 %29, %33, off offset:832 sc0 sc1\n\t"         \
    "global_load_dwordx4 %30, %33, off offset:896 sc0 sc1\n\t"         \
    "global_load_dwordx4 %31, %33, off offset:960 sc0 sc1\n\t"         \
    "s_waitcnt vmcnt(0)"                                               \
    : "=v"(R0[0]), "=v"(R0[1]), "=v"(R0[2]), "=v"(R0[3]),              \
      "=v"(R0[4]), "=v"(R0[5]), "=v"(R0[6]), "=v"(R0[7]),              \
      "=v"(R0[8]), "=v"(R0[9]), "=v"(R0[10]), "=v"(R0[11]),            \
      "=v"(R0[12]), "=v"(R0[13]), "=v"(R0[14]), "=v"(R0[15]),          \
      "=v"(R1[0]), "=v"(R1[1]), "=v"(R1[2]), "=v"(R1[3]),              \
      "=v"(R1[4]), "=v"(R1[5]), "=v"(R1[6]), "=v"(R1[7]),              \
      "=v"(R1[8]), "=v"(R1[9]), "=v"(R1[10]), "=v"(R1[11]),            \
      "=v"(R1[12]), "=v"(R1[13]), "=v"(R1[14]), "=v"(R1[15])           \
    : "v"(a0), "v"(a1) : "memory")

__global__ __launch_bounds__(256, 1) void mclstm_main(
    const float* __restrict__ xin, const float* __restrict__ Wm,
    const float* __restrict__ Um,  const float* __restrict__ k1,
    const float* __restrict__ bias, const float* __restrict__ bias1,
    float* __restrict__ out, unsigned char* __restrict__ ws)
{
    __shared__ __align__(16) short sB[NT * BST];   // 91 KB: Bt[n][k] bf16
    __shared__ float sD[128 * 8];                  // d-gate dump / d values
    __shared__ __align__(16) short sH[128 * SHP];  // 6 KB: h_new slice staging

    const int tid  = threadIdx.x;
    const int wg   = blockIdx.x;
    const int lane = tid & 63;
    const int wave = tid >> 6;
    const int j0   = wg * 16;

    unsigned* arr  = (unsigned*)(ws + OFF_ARR);
    short*    hbuf = (short*)(ws + OFF_HB);
    float*    hfin = (float*)(ws + OFF_HFIN);
    float*    cfin = (float*)(ws + OFF_CFIN);

    // ---- stage weights into LDS: sB[n*BST + k], n in [0,80) ----
    for (int e = tid; e < NT * Kk; e += 256) {
        int n = e % NT, k = e / NT;
        int col = -1;
        if (n < 64)      col = (n >> 4) * Hh + j0 + (n & 15);
        else if (n < 69) col = 4 * Hh + (n - 64);
        float v = 0.f;
        if (col >= 0) v = (k < Ff) ? Wm[(size_t)k * NGc + col]
                                   : Um[(size_t)(k - Ff) * NGc + col];
        sB[n * BST + k] = (short)f2bf(v);
    }

    const int col16 = lane & 15;
    const int quad  = lane >> 4;
    const int kgrp  = quad * 8;

    // bias per n-tile (col = col16)
    float biasreg[5];
#pragma unroll
    for (int nt = 0; nt < 5; ++nt) {
        int col;
        if (nt < 4) col = nt * Hh + j0 + col16;
        else        col = (col16 < 5) ? (4 * Hh + col16) : -1;
        biasreg[nt] = (col >= 0) ? bias[col] : 0.f;
    }

    // per-lane elementwise constants: lane owns hidden unit u = col16
    const float s1v = bias1[j0 + col16];
    const float s2v = bias1[Hh + j0 + col16];
    float kv[5];
#pragma unroll
    for (int g = 0; g < 5; ++g) kv[g] = k1[g * Hh + j0 + col16];
    float cp[2][4] = {{0,0,0,0},{0,0,0,0}};     // c-state for lane's 8 rows

    const int row0 = wave * 32 + col16;         // m-tile 0 row (A-frag)
    const int row1 = wave * 32 + 16 + col16;    // m-tile 1 row

    __syncthreads();

    for (int t = 0; t < Ss; ++t) {
        const short* hcur = hbuf + (size_t)(t & 1) * (Bb * Hh);
        short*      hnext = hbuf + (size_t)((t + 1) & 1) * (Bb * Hh);

        // ---- accumulators (bias-init) ----
        f32x4 acc[5][2];
#pragma unroll
        for (int nt = 0; nt < 5; ++nt)
#pragma unroll
            for (int mt = 0; mt < 2; ++mt) {
                f32x4 z = {biasreg[nt], biasreg[nt], biasreg[nt], biasreg[nt]};
                acc[nt][mt] = z;
            }

        // ---- x_t loads + x@W MFMAs BEFORE the barrier (off critical path) ----
        short8 Ax[2][2];
#pragma unroll
        for (int k0 = 0; k0 < 2; ++k0) {
            int kb = k0 * 32 + kgrp;
            const float* p0 = xin + ((size_t)row0 * Ss + t) * Ff + kb;
            const float* p1 = xin + ((size_t)row1 * Ss + t) * Ff + kb;
            f32x4 f00 = *(const f32x4*)(p0);
            f32x4 f01 = *(const f32x4*)(p0 + 4);
            f32x4 f10 = *(const f32x4*)(p1);
            f32x4 f11 = *(const f32x4*)(p1 + 4);
#pragma unroll
            for (int j = 0; j < 4; ++j) {
                Ax[k0][0][j]     = (short)f2bf(f00[j]); Ax[k0][0][4 + j] = (short)f2bf(f01[j]);
                Ax[k0][1][j]     = (short)f2bf(f10[j]); Ax[k0][1][4 + j] = (short)f2bf(f11[j]);
            }
        }
#pragma unroll
        for (int k0 = 0; k0 < 2; ++k0) {
            int kb = k0 * 32 + kgrp;
#pragma unroll
            for (int nt = 0; nt < 5; ++nt) {
                short8 b = *(const short8*)(sB + (nt * 16 + col16) * BST + kb);
                acc[nt][0] = __builtin_amdgcn_mfma_f32_16x16x32_bf16(Ax[k0][0], b, acc[nt][0], 0, 0, 0);
                acc[nt][1] = __builtin_amdgcn_mfma_f32_16x16x32_bf16(Ax[k0][1], b, acc[nt][1], 0, 0, 0);
            }
        }

        // ---- wait for step-t h to be LLC-visible (scalar relaxed polls) ----
        if (tid < 64) {
            const bool mine = tid < NWG;
            unsigned* fa = arr + (tid & 31) * 32;
            const unsigned tgt = (unsigned)t;
            for (int it = 0; it < (1 << 22); ++it) {
                unsigned v = mine ? __hip_atomic_load(fa, __ATOMIC_RELAXED,
                                                      __HIP_MEMORY_SCOPE_AGENT)
                                  : 0xFFFFFFFFu;
                if (__all((int)(v >= tgt))) break;
                __builtin_amdgcn_s_sleep(1);
            }
        }
        __syncthreads();

        // ---- h loads: 32 pipelined LLC-direct 16B bursts (coalescing) ----
        i32x4a R0v[16], R1v[16];
        {
            unsigned long long a0 = (unsigned long long)
                ((const char*)(hcur + (size_t)row0 * Hh) + quad * 16);
            unsigned long long a1 = (unsigned long long)
                ((const char*)(hcur + (size_t)row1 * Hh) + quad * 16);
            HLOAD32(R0v, R1v, a0, a1);
        }

        // ---- h part (k = 64..575) ----
#pragma unroll
        for (int k0 = 0; k0 < 16; ++k0) {
            short8 a0v = __builtin_bit_cast(short8, R0v[k0]);
            short8 a1v = __builtin_bit_cast(short8, R1v[k0]);
            int kb = 64 + k0 * 32 + kgrp;
#pragma unroll
            for (int nt = 0; nt < 5; ++nt) {
                short8 b = *(const short8*)(sB + (nt * 16 + col16) * BST + kb);
                acc[nt][0] = __builtin_amdgcn_mfma_f32_16x16x32_bf16(a0v, b, acc[nt][0], 0, 0, 0);
                acc[nt][1] = __builtin_amdgcn_mfma_f32_16x16x32_bf16(a1v, b, acc[nt][1], 0, 0, 0);
            }
        }

        // ---- d gate: dump cols 0..4 (tile 4), softmax(tanh(.)) per row ----
        if (col16 < 5) {
#pragma unroll
            for (int mt = 0; mt < 2; ++mt)
#pragma unroll
                for (int j = 0; j < 4; ++j)
                    sD[(wave * 32 + mt * 16 + quad * 4 + j) * 8 + col16] = acc[4][mt][j];
        }
        __syncthreads();
        if (tid < 128) {
            int r = tid;
            float v[5], mx = -1e30f;
#pragma unroll
            for (int c = 0; c < 5; ++c) { v[c] = tanhf(sD[r * 8 + c]); mx = fmaxf(mx, v[c]); }
            float s = 0.f;
#pragma unroll
            for (int c = 0; c < 5; ++c) { v[c] = __expf(v[c] - mx); s += v[c]; }
            float inv = 1.f / s;
#pragma unroll
            for (int c = 0; c < 5; ++c) sD[r * 8 + c] = v[c] * inv;
            if (t == Ss - 1 && wg == 0) {
#pragma unroll
                for (int c = 0; c < 5; ++c) out[1408 + r * 5 + c] = v[c] * inv;
            }
        }
        __syncthreads();

        // ---- cell update: i/f/g/o are tiles 0..3, same lane; h_new -> sH ----
#pragma unroll
        for (int mt = 0; mt < 2; ++mt) {
#pragma unroll
            for (int j = 0; j < 4; ++j) {
                int r = wave * 32 + mt * 16 + quad * 4 + j;
                float i_ = 1.f / (1.f + __expf(-acc[0][mt][j]));
                float f_ = 1.f / (1.f + __expf(-acc[1][mt][j]));
                float g_ = tanhf(acc[2][mt][j]);
                float o_ = 1.f / (1.f + __expf(-acc[3][mt][j]));
                float c1v = tanhf(g_);
                float c5v = cp[mt][j];
                float c3v = f_ * c5v + i_ * g_;
                float c2v = s2v * c3v + (1.f - s2v) * c1v;
                float c4v = s1v * c3v + (1.f - s1v) * c5v;
                const float* dr = sD + r * 8;
                float cn = dr[0] * kv[0] * c1v + dr[1] * kv[1] * c2v + dr[2] * kv[2] * c3v
                         + dr[3] * kv[3] * c4v + dr[4] * kv[4] * c5v;
                float hn = o_ * tanhf(cn);
                cp[mt][j] = cn;
                sH[r * SHP + col16] = (short)f2bf(hn);
                if (t == Ss - 1) {
                    size_t off = (size_t)r * Hh + j0 + col16;
                    hfin[off] = hn;
                    cfin[0 * Bb * Hh + off] = c1v;
                    cfin[1 * Bb * Hh + off] = c2v;
                    cfin[2 * Bb * Hh + off] = c3v;
                    cfin[3 * Bb * Hh + off] = c4v;
                    cfin[4 * Bb * Hh + off] = c5v;
                }
            }
        }
        __syncthreads();                 // sH slice complete

        if (t < Ss - 1) {
            // publish: one coalesced LLC-direct 16B store per thread
            int r = tid >> 1, half = tid & 1;
            i32x4a val = *(const i32x4a*)(sH + r * SHP + half * 8);
            unsigned long long sa = (unsigned long long)
                ((char*)(hnext + (size_t)r * Hh + j0) + half * 16);
            asm volatile("global_store_dwordx4 %0, %1, off sc0 sc1\n\t"
                         "s_waitcnt vmcnt(0)"
                         :: "v"(sa), "v"(val) : "memory");
            __syncthreads();             // all 256 stores LLC-visible
            if (tid == 0)
                __hip_atomic_store(&arr[wg * 32], (unsigned)(t + 1),
                                   __ATOMIC_RELAXED, __HIP_MEMORY_SCOPE_AGENT);
        }
    }
}

// ---- heads: stage A: r1 = relu(h@rw1+rb1); y1[hd] = relu(c_hd@dw1+db1) ----
__global__ __launch_bounds__(256) void stageA(const unsigned char* __restrict__ ws,
    const float* __restrict__ rw1, const float* __restrict__ rb1,
    const float* __restrict__ dw1, const float* __restrict__ db1)
{
    __shared__ float sW[512 * 17];
    const int tid = threadIdx.x;
    const int blk = blockIdx.x;
    const float* hfin = (const float*)(ws + OFF_HFIN);
    const float* cfin = (const float*)(ws + OFF_CFIN);
    float* r1 = (float*)(ws + OFF_R1);
    float* y1 = (float*)(ws + OFF_Y1);

    const float* src; const float* Wm; const float* bv; float* dst; int cblk;
    if (blk < 16) { src = hfin; Wm = rw1; bv = rb1; dst = r1; cblk = blk; }
    else {
        int hd = (blk - 16) >> 4; cblk = (blk - 16) & 15;
        src = cfin + (size_t)hd * Bb * Hh; Wm = dw1; bv = db1;
        dst = y1 + (size_t)hd * Bb * 256;
    }
    for (int e = tid; e < 512 * 16; e += 256) {
        int k = e >> 4, c = e & 15;
        sW[k * 17 + c] = Wm[(size_t)k * 256 + cblk * 16 + c];
    }
    __syncthreads();
    for (int e = tid; e < 128 * 16; e += 256) {
        int r = e >> 4, c = e & 15;
        float a = bv[cblk * 16 + c];
        const float* sp = src + (size_t)r * 512;
        for (int k = 0; k < 512; k += 4) {
            f32x4 h4 = *(const f32x4*)(sp + k);
            a += h4[0] * sW[(k + 0) * 17 + c] + h4[1] * sW[(k + 1) * 17 + c]
               + h4[2] * sW[(k + 2) * 17 + c] + h4[3] * sW[(k + 3) * 17 + c];
        }
        dst[(size_t)r * 256 + cblk * 16 + c] = fmaxf(a, 0.f);
    }
}

// ---- stage B: r2 = relu(r1@rw2+rb2) ----
__global__ __launch_bounds__(256) void stageB(const unsigned char* __restrict__ ws,
    const float* __restrict__ rw2, const float* __restrict__ rb2)
{
    __shared__ float sW[256 * 17];
    const int tid = threadIdx.x;
    const int cblk = blockIdx.x;
    const float* r1 = (const float*)(ws + OFF_R1);
    float* r2 = (float*)(ws + OFF_R2);
    for (int e = tid; e < 256 * 16; e += 256) {
        int k = e >> 4, c = e & 15;
        sW[k * 17 + c] = rw2[(size_t)k * 128 + cblk * 16 + c];
    }
    __syncthreads();
    for (int e = tid; e < 128 * 16; e += 256) {
        int r = e >> 4, c = e & 15;
        float a = rb2[cblk * 16 + c];
        const float* sp = r1 + (size_t)r * 256;
        for (int k = 0; k < 256; k += 4) {
            f32x4 h4 = *(const f32x4*)(sp + k);
            a += h4[0] * sW[(k + 0) * 17 + c] + h4[1] * sW[(k + 1) * 17 + c]
               + h4[2] * sW[(k + 2) * 17 + c] + h4[3] * sW[(k + 3) * 17 + c];
        }
        r2[(size_t)r * 128 + cblk * 16 + c] = fmaxf(a, 0.f);
    }
}

// ---- stage C: BN + final projections + log_softmax ----
__global__ __launch_bounds__(256) void stageC(const unsigned char* __restrict__ ws,
    const float* __restrict__ rbng, const float* __restrict__ rbnb,
    const float* __restrict__ rw3,  const float* __restrict__ rb3,
    const float* __restrict__ dbng, const float* __restrict__ dbnb,
    const float* __restrict__ dw2,  const float* __restrict__ db2,
    float* __restrict__ out)
{
    __shared__ float sc[256], sh[256];
    const int tid = threadIdx.x;
    const int blk = blockIdx.x;
    const float* r2 = (const float*)(ws + OFF_R2);
    const float* y1 = (const float*)(ws + OFF_Y1);
    if (blk == 0) {
        if (tid < 128) {
            int c = tid; float s = 0.f, s2 = 0.f;
            for (int r = 0; r < 128; ++r) { float x = r2[r * 128 + c]; s += x; s2 += x * x; }
            float m = s * (1.f / 128.f), v = s2 * (1.f / 128.f) - m * m;
            float sca = rbng[c] * rsqrtf(v + 1e-5f);
            sc[c] = sca; sh[c] = rbnb[c] - m * sca;
        }
        __syncthreads();
        if (tid < 128) {
            int r = tid; float a = rb3[0];
            for (int c = 0; c < 128; ++c)
                a += (r2[r * 128 + c] * sc[c] + sh[c]) * rw3[c];
            out[r] = a;
        }
    } else {
        int hd = blk - 1;
        const float* y = y1 + (size_t)hd * 128 * 256;
        {
            int c = tid; float s = 0.f, s2 = 0.f;
            for (int r = 0; r < 128; ++r) { float x = y[r * 256 + c]; s += x; s2 += x * x; }
            float m = s * (1.f / 128.f), v = s2 * (1.f / 128.f) - m * m;
            float sca = dbng[c] * rsqrtf(v + 1e-5f);
            sc[c] = sca; sh[c] = dbnb[c] - m * sca;
        }
        __syncthreads();
        if (tid < 128) {
            int r = tid;
            float z0 = db2[0], z1 = db2[1];
            for (int c = 0; c < 256; ++c) {
                float yn = y[r * 256 + c] * sc[c] + sh[c];
                z0 += yn * dw2[c * 2 + 0];
                z1 += yn * dw2[c * 2 + 1];
            }
            float mx = fmaxf(z0, z1);
            float ls = mx + logf(__expf(z0 - mx) + __expf(z1 - mx));
            out[128 + hd * 256 + r * 2 + 0] = z0 - ls;
            out[128 + hd * 256 + r * 2 + 1] = z1 - ls;
        }
    }
}

extern "C" void kernel_launch(void* const* d_in, const int* in_sizes, int n_in,
                              void* d_out, int out_size, void* d_ws, size_t ws_size,
                              hipStream_t stream) {
    const float* x    = (const float*)d_in[0];
    const float* Wm   = (const float*)d_in[1];
    const float* Um   = (const float*)d_in[2];
    const float* k1   = (const float*)d_in[3];
    const float* bias = (const float*)d_in[4];
    const float* b1   = (const float*)d_in[5];
    const float* rw1  = (const float*)d_in[6];
    const float* rb1  = (const float*)d_in[7];
    const float* rw2  = (const float*)d_in[8];
    const float* rb2  = (const float*)d_in[9];
    const float* rbng = (const float*)d_in[10];
    const float* rbnb = (const float*)d_in[11];
    const float* rw3  = (const float*)d_in[12];
    const float* rb3  = (const float*)d_in[13];
    const float* dw1  = (const float*)d_in[14];
    const float* db1  = (const float*)d_in[15];
    const float* dbng = (const float*)d_in[16];
    const float* dbnb = (const float*)d_in[17];
    const float* dw2  = (const float*)d_in[18];
    const float* db2  = (const float*)d_in[19];
    (void)in_sizes; (void)n_in; (void)out_size; (void)ws_size;

    // zero arrival flags + h ping-pong buffers
    hipMemsetAsync(d_ws, 0, OFF_HB + Bb * Hh * 2 * 2, stream);

    mclstm_main<<<NWG, 256, 0, stream>>>(x, Wm, Um, k1, bias, b1,
                                         (float*)d_out, (unsigned char*)d_ws);
    stageA<<<96, 256, 0, stream>>>((const unsigned char*)d_ws, rw1, rb1, dw1, db1);
    stageB<<<8, 256, 0, stream>>>((const unsigned char*)d_ws, rw2, rb2);
    stageC<<<6, 256, 0, stream>>>((const unsigned char*)d_ws, rbng, rbnb, rw3, rb3,
                                  dbng, dbnb, dw2, db2, (float*)d_out);
}

// Round 6
// 3085.513 us; speedup vs baseline: 2.3987x; 2.0627x over previous
//
#include <hip/hip_runtime.h>
#include <hip/hip_bf16.h>
#include <math.h>

#define Bb   128
#define Ss   512
#define Ff   64
#define Hh   512
#define NGc  2053          // 4*H + 5
#define Kk   576           // F + H
#define NGRP 8             // batch-row groups (16 rows each), fully independent
#define NT   80            // padded gate cols per WG (64 gates + 5 d + pad)
#define BST  584           // padded k-stride (shorts) for LDS weights

// workspace layout (bytes)
#define OFF_ARR   0                        // 8 x 128B flag lines (32 dwords each)
#define OFF_HB    4096                     // 2 parities x 8 groups x 16384 B h tiles
#define OFF_HFIN  266240                   // B*H fp32
#define OFF_CFIN  528384                   // 5 x B*H fp32
#define OFF_R1    1839104                  // 128x256 fp32
#define OFF_R2    1970176                  // 128x128 fp32
#define OFF_Y1    2035712                  // 5 x 128x256 fp32

typedef __attribute__((ext_vector_type(8))) short short8;
typedef __attribute__((ext_vector_type(4))) float f32x4;
typedef __attribute__((ext_vector_type(4))) int   i32x4a;

__device__ __forceinline__ unsigned short f2bf(float f) {
    union { float f; unsigned u; } v; v.f = f;
    unsigned r = v.u + 0x7fffu + ((v.u >> 16) & 1u);
    return (unsigned short)(r >> 16);
}

// 4 coalescing LLC-direct 16B loads (one per h k-block), pipelined, one drain.
#define HL4(R, a)                                                      \
  asm volatile(                                                        \
    "global_load_dwordx4 %0, %4, off sc0 sc1\n\t"                      \
    "global_load_dwordx4 %1, %4, off offset:1024 sc0 sc1\n\t"          \
    "global_load_dwordx4 %2, %4, off offset:2048 sc0 sc1\n\t"          \
    "global_load_dwordx4 %3, %4, off offset:3072 sc0 sc1\n\t"          \
    "s_waitcnt vmcnt(0)"                                               \
    : "=v"(R[0]), "=v"(R[1]), "=v"(R[2]), "=v"(R[3])                   \
    : "v"(a) : "memory")

__global__ __launch_bounds__(256, 1) void mclstm_main(
    const float* __restrict__ xin, const float* __restrict__ Wm,
    const float* __restrict__ Um,  const float* __restrict__ k1,
    const float* __restrict__ bias, const float* __restrict__ bias1,
    float* __restrict__ out, unsigned char* __restrict__ ws)
{
    __shared__ __align__(16) short sB[NT * BST];   // 91 KB weights (this WG's 80 cols)
    __shared__ float pred[4][16][84];              // 21.5 KB K-split partial gates
    __shared__ __align__(16) short sH[2 * 16 * 8]; // 512 B h_new staging (tile order)

    const int tid   = threadIdx.x;
    const int bid   = blockIdx.x;
    const int g_id  = bid & 7;        // batch-row group
    const int w_id  = bid >> 3;       // hidden-unit block [0,32)
    const int lane  = tid & 63;
    const int wv    = tid >> 6;
    const int j0    = w_id * 16;
    const int col16 = lane & 15;
    const int quad  = lane >> 4;

    unsigned* flg = (unsigned*)(ws + OFF_ARR) + g_id * 32;
    float*    hfin = (float*)(ws + OFF_HFIN);
    float*    cfin = (float*)(ws + OFF_CFIN);

    // ---- stage weights into LDS: sB[n*BST + k], n in [0,80) ----
    for (int e = tid; e < NT * Kk; e += 256) {
        int n = e % NT, k = e / NT;
        int col = -1;
        if (n < 64)      col = (n >> 4) * Hh + j0 + (n & 15);
        else if (n < 69) col = 4 * Hh + (n - 64);
        float v = 0.f;
        if (col >= 0) v = (k < Ff) ? Wm[(size_t)k * NGc + col]
                                   : Um[(size_t)(k - Ff) * NGc + col];
        sB[n * BST + k] = (short)f2bf(v);
    }

    // ---- per-thread cell constants: thread owns (row=tid>>4, unit=tid&15) ----
    const int rrow = tid >> 4, uu = tid & 15;
    const int u_g  = j0 + uu;
    const float bi = bias[0 * Hh + u_g], bf = bias[1 * Hh + u_g];
    const float bg = bias[2 * Hh + u_g], bo = bias[3 * Hh + u_g];
    float bd[5], kv[5];
#pragma unroll
    for (int c = 0; c < 5; ++c) { bd[c] = bias[4 * Hh + c]; kv[c] = k1[c * Hh + u_g]; }
    const float s1v = bias1[u_g], s2v = bias1[Hh + u_g];
    float cpreg = 0.f;

    __syncthreads();

    for (int t = 0; t < Ss; ++t) {
        char* hcur = (char*)ws + OFF_HB + (((t & 1) * 8 + g_id) * 16384);
        char* hnxt = (char*)ws + OFF_HB + ((((t + 1) & 1) * 8 + g_id) * 16384);

        f32x4 acc[5];
#pragma unroll
        for (int nt = 0; nt < 5; ++nt) { f32x4 z = {0.f, 0.f, 0.f, 0.f}; acc[nt] = z; }

        // ---- wave 3 prefetches x fragments (independent of flags) ----
        short8 Ax[2];
        if (wv == 3) {
#pragma unroll
            for (int kbx = 0; kbx < 2; ++kbx) {
                const float* p = xin + ((size_t)(16 * g_id + col16) * Ss + t) * Ff
                               + kbx * 32 + quad * 8;
                f32x4 f0 = *(const f32x4*)(p);
                f32x4 f1 = *(const f32x4*)(p + 4);
#pragma unroll
                for (int j = 0; j < 4; ++j) {
                    Ax[kbx][j]     = (short)f2bf(f0[j]);
                    Ax[kbx][4 + j] = (short)f2bf(f1[j]);
                }
            }
        }

        // ---- hot poll (all waves; compact 128B flag line; no s_sleep) ----
        {
            unsigned* fp = flg + (lane & 31);
            const unsigned tgt = (unsigned)t;
            for (;;) {
                unsigned v = __hip_atomic_load(fp, __ATOMIC_RELAXED,
                                               __HIP_MEMORY_SCOPE_AGENT);
                if (__all((int)(v >= tgt))) break;
            }
        }

        // ---- this wave's 4 h k-blocks: coalesced LLC-direct tile loads ----
        i32x4a Rh[4];
        {
            unsigned long long hb = (unsigned long long)
                (hcur + (wv * 4) * 1024 + quad * 256 + col16 * 16);
            HL4(Rh, hb);
        }

        // ---- MFMAs: x part (wave 3) + this wave's h part ----
        if (wv == 3) {
#pragma unroll
            for (int kbx = 0; kbx < 2; ++kbx) {
                int kk = kbx * 32 + quad * 8;
#pragma unroll
                for (int nt = 0; nt < 5; ++nt) {
                    short8 b = *(const short8*)(sB + (nt * 16 + col16) * BST + kk);
                    acc[nt] = __builtin_amdgcn_mfma_f32_16x16x32_bf16(Ax[kbx], b, acc[nt], 0, 0, 0);
                }
            }
        }
#pragma unroll
        for (int i = 0; i < 4; ++i) {
            short8 a = __builtin_bit_cast(short8, Rh[i]);
            int kk = 64 + (wv * 4 + i) * 32 + quad * 8;
#pragma unroll
            for (int nt = 0; nt < 5; ++nt) {
                short8 b = *(const short8*)(sB + (nt * 16 + col16) * BST + kk);
                acc[nt] = __builtin_amdgcn_mfma_f32_16x16x32_bf16(a, b, acc[nt], 0, 0, 0);
            }
        }

        // ---- write K-split partials ----
#pragma unroll
        for (int nt = 0; nt < 5; ++nt)
#pragma unroll
            for (int j = 0; j < 4; ++j)
                pred[wv][quad * 4 + j][nt * 16 + col16] = acc[nt][j];
        __syncthreads();

        // ---- reduce + cell update: one (row,unit) per thread ----
        {
            float gi = bi, gf = bf, gg = bg, go = bo;
            float dv[5];
#pragma unroll
            for (int c = 0; c < 5; ++c) dv[c] = bd[c];
#pragma unroll
            for (int w = 0; w < 4; ++w) {
                const float* pr = &pred[w][rrow][0];
                gi += pr[uu]; gf += pr[16 + uu]; gg += pr[32 + uu]; go += pr[48 + uu];
#pragma unroll
                for (int c = 0; c < 5; ++c) dv[c] += pr[64 + c];
            }
            float mx = -1e30f;
#pragma unroll
            for (int c = 0; c < 5; ++c) { dv[c] = tanhf(dv[c]); mx = fmaxf(mx, dv[c]); }
            float sden = 0.f;
#pragma unroll
            for (int c = 0; c < 5; ++c) { dv[c] = __expf(dv[c] - mx); sden += dv[c]; }
            float inv = 1.f / sden;
#pragma unroll
            for (int c = 0; c < 5; ++c) dv[c] *= inv;

            float i_ = 1.f / (1.f + __expf(-gi));
            float f_ = 1.f / (1.f + __expf(-gf));
            float g_ = tanhf(gg);
            float o_ = 1.f / (1.f + __expf(-go));
            float c1v = tanhf(g_);
            float c5v = cpreg;
            float c3v = f_ * c5v + i_ * g_;
            float c2v = s2v * c3v + (1.f - s2v) * c1v;
            float c4v = s1v * c3v + (1.f - s1v) * c5v;
            float cn = dv[0] * kv[0] * c1v + dv[1] * kv[1] * c2v + dv[2] * kv[2] * c3v
                     + dv[3] * kv[3] * c4v + dv[4] * kv[4] * c5v;
            float hn = o_ * tanhf(cn);
            cpreg = cn;
            sH[((uu >> 3) * 16 + rrow) * 8 + (uu & 7)] = (short)f2bf(hn);

            if (t == Ss - 1) {
                size_t off = (size_t)(16 * g_id + rrow) * Hh + u_g;
                hfin[off] = hn;
                cfin[0 * Bb * Hh + off] = c1v;
                cfin[1 * Bb * Hh + off] = c2v;
                cfin[2 * Bb * Hh + off] = c3v;
                cfin[3 * Bb * Hh + off] = c4v;
                cfin[4 * Bb * Hh + off] = c5v;
                if (w_id == 0 && uu == 0) {
#pragma unroll
                    for (int c = 0; c < 5; ++c)
                        out[1408 + (16 * g_id + rrow) * 5 + c] = dv[c];
                }
            }
        }
        __syncthreads();

        // ---- publish slice (wave0 lanes 0..31) + flag, single wave-ordered chain ----
        if (t < Ss - 1 && tid < 32) {
            int qp = tid >> 4, r = tid & 15;
            i32x4a val = *(const i32x4a*)(sH + (qp * 16 + r) * 8);
            unsigned long long dst = (unsigned long long)
                (hnxt + (w_id >> 1) * 1024 + ((w_id & 1) * 2 + qp) * 256 + r * 16);
            asm volatile("global_store_dwordx4 %0, %1, off sc0 sc1\n\t"
                         "s_waitcnt vmcnt(0)"
                         :: "v"(dst), "v"(val) : "memory");
            if (tid == 0)
                __hip_atomic_store(&flg[w_id], (unsigned)(t + 1),
                                   __ATOMIC_RELAXED, __HIP_MEMORY_SCOPE_AGENT);
        }
    }
}

// ---- heads: stage A: r1 = relu(h@rw1+rb1); y1[hd] = relu(c_hd@dw1+db1) ----
__global__ __launch_bounds__(256) void stageA(const unsigned char* __restrict__ ws,
    const float* __restrict__ rw1, const float* __restrict__ rb1,
    const float* __restrict__ dw1, const float* __restrict__ db1)
{
    __shared__ float sW[512 * 17];
    const int tid = threadIdx.x;
    const int blk = blockIdx.x;
    const float* hfin = (const float*)(ws + OFF_HFIN);
    const float* cfin = (const float*)(ws + OFF_CFIN);
    float* r1 = (float*)(ws + OFF_R1);
    float* y1 = (float*)(ws + OFF_Y1);

    const float* src; const float* Wm; const float* bv; float* dst; int cblk;
    if (blk < 16) { src = hfin; Wm = rw1; bv = rb1; dst = r1; cblk = blk; }
    else {
        int hd = (blk - 16) >> 4; cblk = (blk - 16) & 15;
        src = cfin + (size_t)hd * Bb * Hh; Wm = dw1; bv = db1;
        dst = y1 + (size_t)hd * Bb * 256;
    }
    for (int e = tid; e < 512 * 16; e += 256) {
        int k = e >> 4, c = e & 15;
        sW[k * 17 + c] = Wm[(size_t)k * 256 + cblk * 16 + c];
    }
    __syncthreads();
    for (int e = tid; e < 128 * 16; e += 256) {
        int r = e >> 4, c = e & 15;
        float a = bv[cblk * 16 + c];
        const float* sp = src + (size_t)r * 512;
        for (int k = 0; k < 512; k += 4) {
            f32x4 h4 = *(const f32x4*)(sp + k);
            a += h4[0] * sW[(k + 0) * 17 + c] + h4[1] * sW[(k + 1) * 17 + c]
               + h4[2] * sW[(k + 2) * 17 + c] + h4[3] * sW[(k + 3) * 17 + c];
        }
        dst[(size_t)r * 256 + cblk * 16 + c] = fmaxf(a, 0.f);
    }
}

// ---- stage B: r2 = relu(r1@rw2+rb2) ----
__global__ __launch_bounds__(256) void stageB(const unsigned char* __restrict__ ws,
    const float* __restrict__ rw2, const float* __restrict__ rb2)
{
    __shared__ float sW[256 * 17];
    const int tid = threadIdx.x;
    const int cblk = blockIdx.x;
    const float* r1 = (const float*)(ws + OFF_R1);
    float* r2 = (float*)(ws + OFF_R2);
    for (int e = tid; e < 256 * 16; e += 256) {
        int k = e >> 4, c = e & 15;
        sW[k * 17 + c] = rw2[(size_t)k * 128 + cblk * 16 + c];
    }
    __syncthreads();
    for (int e = tid; e < 128 * 16; e += 256) {
        int r = e >> 4, c = e & 15;
        float a = rb2[cblk * 16 + c];
        const float* sp = r1 + (size_t)r * 256;
        for (int k = 0; k < 256; k += 4) {
            f32x4 h4 = *(const f32x4*)(sp + k);
            a += h4[0] * sW[(k + 0) * 17 + c] + h4[1] * sW[(k + 1) * 17 + c]
               + h4[2] * sW[(k + 2) * 17 + c] + h4[3] * sW[(k + 3) * 17 + c];
        }
        r2[(size_t)r * 128 + cblk * 16 + c] = fmaxf(a, 0.f);
    }
}

// ---- stage C: BN + final projections + log_softmax ----
__global__ __launch_bounds__(256) void stageC(const unsigned char* __restrict__ ws,
    const float* __restrict__ rbng, const float* __restrict__ rbnb,
    const float* __restrict__ rw3,  const float* __restrict__ rb3,
    const float* __restrict__ dbng, const float* __restrict__ dbnb,
    const float* __restrict__ dw2,  const float* __restrict__ db2,
    float* __restrict__ out)
{
    __shared__ float sc[256], sh[256];
    const int tid = threadIdx.x;
    const int blk = blockIdx.x;
    const float* r2 = (const float*)(ws + OFF_R2);
    const float* y1 = (const float*)(ws + OFF_Y1);
    if (blk == 0) {
        if (tid < 128) {
            int c = tid; float s = 0.f, s2 = 0.f;
            for (int r = 0; r < 128; ++r) { float x = r2[r * 128 + c]; s += x; s2 += x * x; }
            float m = s * (1.f / 128.f), v = s2 * (1.f / 128.f) - m * m;
            float sca = rbng[c] * rsqrtf(v + 1e-5f);
            sc[c] = sca; sh[c] = rbnb[c] - m * sca;
        }
        __syncthreads();
        if (tid < 128) {
            int r = tid; float a = rb3[0];
            for (int c = 0; c < 128; ++c)
                a += (r2[r * 128 + c] * sc[c] + sh[c]) * rw3[c];
            out[r] = a;
        }
    } else {
        int hd = blk - 1;
        const float* y = y1 + (size_t)hd * 128 * 256;
        {
            int c = tid; float s = 0.f, s2 = 0.f;
            for (int r = 0; r < 128; ++r) { float x = y[r * 256 + c]; s += x; s2 += x * x; }
            float m = s * (1.f / 128.f), v = s2 * (1.f / 128.f) - m * m;
            float sca = dbng[c] * rsqrtf(v + 1e-5f);
            sc[c] = sca; sh[c] = dbnb[c] - m * sca;
        }
        __syncthreads();
        if (tid < 128) {
            int r = tid;
            float z0 = db2[0], z1 = db2[1];
            for (int c = 0; c < 256; ++c) {
                float yn = y[r * 256 + c] * sc[c] + sh[c];
                z0 += yn * dw2[c * 2 + 0];
                z1 += yn * dw2[c * 2 + 1];
            }
            float mx = fmaxf(z0, z1);
            float ls = mx + logf(__expf(z0 - mx) + __expf(z1 - mx));
            out[128 + hd * 256 + r * 2 + 0] = z0 - ls;
            out[128 + hd * 256 + r * 2 + 1] = z1 - ls;
        }
    }
}

extern "C" void kernel_launch(void* const* d_in, const int* in_sizes, int n_in,
                              void* d_out, int out_size, void* d_ws, size_t ws_size,
                              hipStream_t stream) {
    const float* x    = (const float*)d_in[0];
    const float* Wm   = (const float*)d_in[1];
    const float* Um   = (const float*)d_in[2];
    const float* k1   = (const float*)d_in[3];
    const float* bias = (const float*)d_in[4];
    const float* b1   = (const float*)d_in[5];
    const float* rw1  = (const float*)d_in[6];
    const float* rb1  = (const float*)d_in[7];
    const float* rw2  = (const float*)d_in[8];
    const float* rb2  = (const float*)d_in[9];
    const float* rbng = (const float*)d_in[10];
    const float* rbnb = (const float*)d_in[11];
    const float* rw3  = (const float*)d_in[12];
    const float* rb3  = (const float*)d_in[13];
    const float* dw1  = (const float*)d_in[14];
    const float* db1  = (const float*)d_in[15];
    const float* dbng = (const float*)d_in[16];
    const float* dbnb = (const float*)d_in[17];
    const float* dw2  = (const float*)d_in[18];
    const float* db2  = (const float*)d_in[19];
    (void)in_sizes; (void)n_in; (void)out_size; (void)ws_size;

    // zero flags + both h tile parities
    hipMemsetAsync(d_ws, 0, OFF_HFIN, stream);

    mclstm_main<<<256, 256, 0, stream>>>(x, Wm, Um, k1, bias, b1,
                                         (float*)d_out, (unsigned char*)d_ws);
    stageA<<<96, 256, 0, stream>>>((const unsigned char*)d_ws, rw1, rb1, dw1, db1);
    stageB<<<8, 256, 0, stream>>>((const unsigned char*)d_ws, rw2, rb2);
    stageC<<<6, 256, 0, stream>>>((const unsigned char*)d_ws, rbng, rbnb, rw3, rb3,
                                  dbng, dbnb, dw2, db2, (float*)d_out);
}

// Round 7
// 2281.859 us; speedup vs baseline: 3.2435x; 1.3522x over previous
//
#include <hip/hip_runtime.h>
#include <hip/hip_bf16.h>
#include <math.h>

#define Bb   128
#define Ss   512
#define Ff   64
#define Hh   512
#define NGc  2053          // 4*H + 5
#define Kk   576           // F + H
#define NT   80            // padded gate cols per WG (64 gates + 5 d + pad)
#define BST  584           // padded k-stride (shorts) for LDS weights

// workspace layout (bytes)
#define OFF_ARR   0                        // 8 x 128B flag lines (32 dwords each)
#define OFF_HB    4096                     // 2 parities x 8 groups x 16384 B h tiles
#define OFF_HFIN  266240                   // B*H fp32
#define OFF_CFIN  528384                   // 5 x B*H fp32
#define OFF_R1    1839104                  // 128x256 fp32
#define OFF_R2    1970176                  // 128x128 fp32
#define OFF_Y1    2035712                  // 5 x 128x256 fp32

typedef __attribute__((ext_vector_type(8))) short short8;
typedef __attribute__((ext_vector_type(4))) float f32x4;
typedef __attribute__((ext_vector_type(4))) int   i32x4a;

__device__ __forceinline__ unsigned short f2bf(float f) {
    union { float f; unsigned u; } v; v.f = f;
    unsigned r = v.u + 0x7fffu + ((v.u >> 16) & 1u);
    return (unsigned short)(r >> 16);
}

// overflow-safe fast tanh: t = exp(-2|x|) in (0,1]; tanh = sign(x)*(1-t)/(1+t)
__device__ __forceinline__ float ftanh(float x) {
    float ax = fabsf(x);
    float t  = __expf(-2.f * ax);
    float r  = (1.f - t) / (1.f + t);
    return copysignf(r, x);
}
__device__ __forceinline__ float fsig(float x) {
    return 1.f / (1.f + __expf(-x));
}

// 4 coalescing LLC-direct 16B loads (one per h k-block), pipelined, one drain.
#define HL4(R, a)                                                      \
  asm volatile(                                                        \
    "global_load_dwordx4 %0, %4, off sc0 sc1\n\t"                      \
    "global_load_dwordx4 %1, %4, off offset:1024 sc0 sc1\n\t"          \
    "global_load_dwordx4 %2, %4, off offset:2048 sc0 sc1\n\t"          \
    "global_load_dwordx4 %3, %4, off offset:3072 sc0 sc1\n\t"          \
    "s_waitcnt vmcnt(0)"                                               \
    : "=v"(R[0]), "=v"(R[1]), "=v"(R[2]), "=v"(R[3])                   \
    : "v"(a) : "memory")

__global__ __launch_bounds__(256, 1) void mclstm_main(
    const float* __restrict__ xin, const float* __restrict__ Wm,
    const float* __restrict__ Um,  const float* __restrict__ k1,
    const float* __restrict__ bias, const float* __restrict__ bias1,
    float* __restrict__ out, unsigned char* __restrict__ ws)
{
    __shared__ __align__(16) short sB[NT * BST];    // 91 KB weights (this WG's 80 cols)
    __shared__ __align__(16) float pred[4][5][16][20]; // 25.6 KB K-split partials
    __shared__ __align__(16) short sH[2 * 16 * 8];  // 512 B h_new staging (tile order)

    const int tid   = threadIdx.x;
    const int bid   = blockIdx.x;
    const int g_id  = bid & 7;        // batch-row group
    const int w_id  = bid >> 3;       // hidden-unit block [0,32)
    const int lane  = tid & 63;
    const int wv    = tid >> 6;
    const int j0    = w_id * 16;
    const int col16 = lane & 15;
    const int quad  = lane >> 4;

    unsigned* flg  = (unsigned*)(ws + OFF_ARR) + g_id * 32;
    float*    hfin = (float*)(ws + OFF_HFIN);
    float*    cfin = (float*)(ws + OFF_CFIN);

    // ---- stage weights into LDS: sB[n*BST + k], n in [0,80) ----
    for (int e = tid; e < NT * Kk; e += 256) {
        int n = e % NT, k = e / NT;
        int col = -1;
        if (n < 64)      col = (n >> 4) * Hh + j0 + (n & 15);
        else if (n < 69) col = 4 * Hh + (n - 64);
        float v = 0.f;
        if (col >= 0) v = (k < Ff) ? Wm[(size_t)k * NGc + col]
                                   : Um[(size_t)(k - Ff) * NGc + col];
        sB[n * BST + k] = (short)f2bf(v);
    }

    // ---- per-thread cell constants: thread owns (row=tid>>4, unit=tid&15) ----
    const int rrow = tid >> 4, uu = tid & 15;
    const int u_g  = j0 + uu;
    const float bi = bias[0 * Hh + u_g], bf = bias[1 * Hh + u_g];
    const float bg = bias[2 * Hh + u_g], bo = bias[3 * Hh + u_g];
    float bd[5], kv[5];
#pragma unroll
    for (int c = 0; c < 5; ++c) { bd[c] = bias[4 * Hh + c]; kv[c] = k1[c * Hh + u_g]; }
    const float s1v = bias1[u_g], s2v = bias1[Hh + u_g];
    float cpreg = 0.f;

    __syncthreads();

    for (int t = 0; t < Ss; ++t) {
        char* hcur = (char*)ws + OFF_HB + (((t & 1) * 8 + g_id) * 16384);
        char* hnxt = (char*)ws + OFF_HB + ((((t + 1) & 1) * 8 + g_id) * 16384);

        f32x4 acc[5];
#pragma unroll
        for (int nt = 0; nt < 5; ++nt) { f32x4 z = {0.f, 0.f, 0.f, 0.f}; acc[nt] = z; }

        // ---- waves 0,1: own one x k-block; load + MFMA BEFORE poll ----
        if (wv < 2) {
            short8 Ax;
            const float* p = xin + ((size_t)(16 * g_id + col16) * Ss + t) * Ff
                           + wv * 32 + quad * 8;
            f32x4 f0 = *(const f32x4*)(p);
            f32x4 f1 = *(const f32x4*)(p + 4);
#pragma unroll
            for (int j = 0; j < 4; ++j) {
                Ax[j]     = (short)f2bf(f0[j]);
                Ax[4 + j] = (short)f2bf(f1[j]);
            }
            int kk = wv * 32 + quad * 8;
#pragma unroll
            for (int nt = 0; nt < 5; ++nt) {
                short8 b = *(const short8*)(sB + (nt * 16 + col16) * BST + kk);
                acc[nt] = __builtin_amdgcn_mfma_f32_16x16x32_bf16(Ax, b, acc[nt], 0, 0, 0);
            }
        }

        // ---- per-wave poll: only this wave's 8 producer flags (lanes 0..7) ----
        {
            unsigned* fp = flg + wv * 8 + (lane & 7);
            const bool mine = lane < 8;
            const unsigned tgt = (unsigned)t;
            for (;;) {
                unsigned v = mine ? __hip_atomic_load(fp, __ATOMIC_RELAXED,
                                                      __HIP_MEMORY_SCOPE_AGENT)
                                  : 0xFFFFFFFFu;
                if (__all((int)(v >= tgt))) break;
            }
        }

        // ---- this wave's 4 h k-blocks: coalesced LLC-direct tile loads ----
        i32x4a Rh[4];
        {
            unsigned long long hb = (unsigned long long)
                (hcur + (wv * 4) * 1024 + quad * 256 + col16 * 16);
            HL4(Rh, hb);
        }

#pragma unroll
        for (int i = 0; i < 4; ++i) {
            short8 a = __builtin_bit_cast(short8, Rh[i]);
            int kk = 64 + (wv * 4 + i) * 32 + quad * 8;
#pragma unroll
            for (int nt = 0; nt < 5; ++nt) {
                short8 b = *(const short8*)(sB + (nt * 16 + col16) * BST + kk);
                acc[nt] = __builtin_amdgcn_mfma_f32_16x16x32_bf16(a, b, acc[nt], 0, 0, 0);
            }
        }

        // ---- write K-split partials: one ds_write_b128 per nt (BW-optimal) ----
#pragma unroll
        for (int nt = 0; nt < 5; ++nt)
            *(f32x4*)&pred[wv][nt][col16][quad * 4] = acc[nt];
        __syncthreads();

        // ---- reduce + cell update: one (row,unit) per thread; reads 2-way free ----
        {
            float gi = bi, gf = bf, gg = bg, go = bo;
            float dv[5];
#pragma unroll
            for (int c = 0; c < 5; ++c) dv[c] = bd[c];
#pragma unroll
            for (int w = 0; w < 4; ++w) {
                gi += pred[w][0][uu][rrow];
                gf += pred[w][1][uu][rrow];
                gg += pred[w][2][uu][rrow];
                go += pred[w][3][uu][rrow];
#pragma unroll
                for (int c = 0; c < 5; ++c) dv[c] += pred[w][4][c][rrow];
            }
            // softmax(tanh(.)): tanh in [-1,1] -> no max-subtraction needed
            float sden = 0.f;
#pragma unroll
            for (int c = 0; c < 5; ++c) { dv[c] = __expf(ftanh(dv[c])); sden += dv[c]; }
            float inv = 1.f / sden;
#pragma unroll
            for (int c = 0; c < 5; ++c) dv[c] *= inv;

            float i_ = fsig(gi);
            float f_ = fsig(gf);
            float g_ = ftanh(gg);
            float o_ = fsig(go);
            float c1v = ftanh(g_);
            float c5v = cpreg;
            float c3v = f_ * c5v + i_ * g_;
            float c2v = s2v * c3v + (1.f - s2v) * c1v;
            float c4v = s1v * c3v + (1.f - s1v) * c5v;
            float cn = dv[0] * kv[0] * c1v + dv[1] * kv[1] * c2v + dv[2] * kv[2] * c3v
                     + dv[3] * kv[3] * c4v + dv[4] * kv[4] * c5v;
            float hn = o_ * ftanh(cn);
            cpreg = cn;
            sH[((uu >> 3) * 16 + rrow) * 8 + (uu & 7)] = (short)f2bf(hn);

            if (t == Ss - 1) {
                size_t off = (size_t)(16 * g_id + rrow) * Hh + u_g;
                hfin[off] = hn;
                cfin[0 * Bb * Hh + off] = c1v;
                cfin[1 * Bb * Hh + off] = c2v;
                cfin[2 * Bb * Hh + off] = c3v;
                cfin[3 * Bb * Hh + off] = c4v;
                cfin[4 * Bb * Hh + off] = c5v;
                if (w_id == 0 && uu == 0) {
#pragma unroll
                    for (int c = 0; c < 5; ++c)
                        out[1408 + (16 * g_id + rrow) * 5 + c] = dv[c];
                }
            }
        }
        __syncthreads();

        // ---- publish slice (wave0 lanes 0..31) + flag, wave-ordered chain ----
        if (t < Ss - 1 && tid < 32) {
            int qp = tid >> 4, r = tid & 15;
            i32x4a val = *(const i32x4a*)(sH + (qp * 16 + r) * 8);
            unsigned long long dst = (unsigned long long)
                (hnxt + (w_id >> 1) * 1024 + ((w_id & 1) * 2 + qp) * 256 + r * 16);
            asm volatile("global_store_dwordx4 %0, %1, off sc0 sc1\n\t"
                         "s_waitcnt vmcnt(0)"
                         :: "v"(dst), "v"(val) : "memory");
            if (tid == 0)
                __hip_atomic_store(&flg[w_id], (unsigned)(t + 1),
                                   __ATOMIC_RELAXED, __HIP_MEMORY_SCOPE_AGENT);
        }
    }
}

// ---- heads: stage A: r1 = relu(h@rw1+rb1); y1[hd] = relu(c_hd@dw1+db1) ----
__global__ __launch_bounds__(256) void stageA(const unsigned char* __restrict__ ws,
    const float* __restrict__ rw1, const float* __restrict__ rb1,
    const float* __restrict__ dw1, const float* __restrict__ db1)
{
    __shared__ float sW[512 * 17];
    const int tid = threadIdx.x;
    const int blk = blockIdx.x;
    const float* hfin = (const float*)(ws + OFF_HFIN);
    const float* cfin = (const float*)(ws + OFF_CFIN);
    float* r1 = (float*)(ws + OFF_R1);
    float* y1 = (float*)(ws + OFF_Y1);

    const float* src; const float* Wm; const float* bv; float* dst; int cblk;
    if (blk < 16) { src = hfin; Wm = rw1; bv = rb1; dst = r1; cblk = blk; }
    else {
        int hd = (blk - 16) >> 4; cblk = (blk - 16) & 15;
        src = cfin + (size_t)hd * Bb * Hh; Wm = dw1; bv = db1;
        dst = y1 + (size_t)hd * Bb * 256;
    }
    for (int e = tid; e < 512 * 16; e += 256) {
        int k = e >> 4, c = e & 15;
        sW[k * 17 + c] = Wm[(size_t)k * 256 + cblk * 16 + c];
    }
    __syncthreads();
    for (int e = tid; e < 128 * 16; e += 256) {
        int r = e >> 4, c = e & 15;
        float a = bv[cblk * 16 + c];
        const float* sp = src + (size_t)r * 512;
        for (int k = 0; k < 512; k += 4) {
            f32x4 h4 = *(const f32x4*)(sp + k);
            a += h4[0] * sW[(k + 0) * 17 + c] + h4[1] * sW[(k + 1) * 17 + c]
               + h4[2] * sW[(k + 2) * 17 + c] + h4[3] * sW[(k + 3) * 17 + c];
        }
        dst[(size_t)r * 256 + cblk * 16 + c] = fmaxf(a, 0.f);
    }
}

// ---- stage B: r2 = relu(r1@rw2+rb2) ----
__global__ __launch_bounds__(256) void stageB(const unsigned char* __restrict__ ws,
    const float* __restrict__ rw2, const float* __restrict__ rb2)
{
    __shared__ float sW[256 * 17];
    const int tid = threadIdx.x;
    const int cblk = blockIdx.x;
    const float* r1 = (const float*)(ws + OFF_R1);
    float* r2 = (float*)(ws + OFF_R2);
    for (int e = tid; e < 256 * 16; e += 256) {
        int k = e >> 4, c = e & 15;
        sW[k * 17 + c] = rw2[(size_t)k * 128 + cblk * 16 + c];
    }
    __syncthreads();
    for (int e = tid; e < 128 * 16; e += 256) {
        int r = e >> 4, c = e & 15;
        float a = rb2[cblk * 16 + c];
        const float* sp = r1 + (size_t)r * 256;
        for (int k = 0; k < 256; k += 4) {
            f32x4 h4 = *(const f32x4*)(sp + k);
            a += h4[0] * sW[(k + 0) * 17 + c] + h4[1] * sW[(k + 1) * 17 + c]
               + h4[2] * sW[(k + 2) * 17 + c] + h4[3] * sW[(k + 3) * 17 + c];
        }
        r2[(size_t)r * 128 + cblk * 16 + c] = fmaxf(a, 0.f);
    }
}

// ---- stage C: BN + final projections + log_softmax ----
__global__ __launch_bounds__(256) void stageC(const unsigned char* __restrict__ ws,
    const float* __restrict__ rbng, const float* __restrict__ rbnb,
    const float* __restrict__ rw3,  const float* __restrict__ rb3,
    const float* __restrict__ dbng, const float* __restrict__ dbnb,
    const float* __restrict__ dw2,  const float* __restrict__ db2,
    float* __restrict__ out)
{
    __shared__ float sc[256], sh[256];
    const int tid = threadIdx.x;
    const int blk = blockIdx.x;
    const float* r2 = (const float*)(ws + OFF_R2);
    const float* y1 = (const float*)(ws + OFF_Y1);
    if (blk == 0) {
        if (tid < 128) {
            int c = tid; float s = 0.f, s2 = 0.f;
            for (int r = 0; r < 128; ++r) { float x = r2[r * 128 + c]; s += x; s2 += x * x; }
            float m = s * (1.f / 128.f), v = s2 * (1.f / 128.f) - m * m;
            float sca = rbng[c] * rsqrtf(v + 1e-5f);
            sc[c] = sca; sh[c] = rbnb[c] - m * sca;
        }
        __syncthreads();
        if (tid < 128) {
            int r = tid; float a = rb3[0];
            for (int c = 0; c < 128; ++c)
                a += (r2[r * 128 + c] * sc[c] + sh[c]) * rw3[c];
            out[r] = a;
        }
    } else {
        int hd = blk - 1;
        const float* y = y1 + (size_t)hd * 128 * 256;
        {
            int c = tid; float s = 0.f, s2 = 0.f;
            for (int r = 0; r < 128; ++r) { float x = y[r * 256 + c]; s += x; s2 += x * x; }
            float m = s * (1.f / 128.f), v = s2 * (1.f / 128.f) - m * m;
            float sca = dbng[c] * rsqrtf(v + 1e-5f);
            sc[c] = sca; sh[c] = dbnb[c] - m * sca;
        }
        __syncthreads();
        if (tid < 128) {
            int r = tid;
            float z0 = db2[0], z1 = db2[1];
            for (int c = 0; c < 256; ++c) {
                float yn = y[r * 256 + c] * sc[c] + sh[c];
                z0 += yn * dw2[c * 2 + 0];
                z1 += yn * dw2[c * 2 + 1];
            }
            float mx = fmaxf(z0, z1);
            float ls = mx + logf(__expf(z0 - mx) + __expf(z1 - mx));
            out[128 + hd * 256 + r * 2 + 0] = z0 - ls;
            out[128 + hd * 256 + r * 2 + 1] = z1 - ls;
        }
    }
}

extern "C" void kernel_launch(void* const* d_in, const int* in_sizes, int n_in,
                              void* d_out, int out_size, void* d_ws, size_t ws_size,
                              hipStream_t stream) {
    const float* x    = (const float*)d_in[0];
    const float* Wm   = (const float*)d_in[1];
    const float* Um   = (const float*)d_in[2];
    const float* k1   = (const float*)d_in[3];
    const float* bias = (const float*)d_in[4];
    const float* b1   = (const float*)d_in[5];
    const float* rw1  = (const float*)d_in[6];
    const float* rb1  = (const float*)d_in[7];
    const float* rw2  = (const float*)d_in[8];
    const float* rb2  = (const float*)d_in[9];
    const float* rbng = (const float*)d_in[10];
    const float* rbnb = (const float*)d_in[11];
    const float* rw3  = (const float*)d_in[12];
    const float* rb3  = (const float*)d_in[13];
    const float* dw1  = (const float*)d_in[14];
    const float* db1  = (const float*)d_in[15];
    const float* dbng = (const float*)d_in[16];
    const float* dbnb = (const float*)d_in[17];
    const float* dw2  = (const float*)d_in[18];
    const float* db2  = (const float*)d_in[19];
    (void)in_sizes; (void)n_in; (void)out_size; (void)ws_size;

    // zero flags + both h tile parities
    hipMemsetAsync(d_ws, 0, OFF_HFIN, stream);

    mclstm_main<<<256, 256, 0, stream>>>(x, Wm, Um, k1, bias, b1,
                                         (float*)d_out, (unsigned char*)d_ws);
    stageA<<<96, 256, 0, stream>>>((const unsigned char*)d_ws, rw1, rb1, dw1, db1);
    stageB<<<8, 256, 0, stream>>>((const unsigned char*)d_ws, rw2, rb2);
    stageC<<<6, 256, 0, stream>>>((const unsigned char*)d_ws, rbng, rbnb, rw3, rb3,
                                  dbng, dbnb, dw2, db2, (float*)d_out);
}

// Round 8
// 1775.513 us; speedup vs baseline: 4.1685x; 1.2852x over previous
//
#include <hip/hip_runtime.h>
#include <hip/hip_bf16.h>
#include <math.h>

#define Bb   128
#define Ss   512
#define Ff   64
#define Hh   512
#define NGc  2053          // 4*H + 5
#define Kk   576           // F + H

// workspace layout (bytes)
#define OFF_ARR   0                        // 8 x 128B flag lines (32 dwords each)
#define OFF_HB    4096                     // 2 parities x 8 groups x 16384 B h tiles
#define OFF_HFIN  266240                   // B*H fp32
#define OFF_CFIN  528384                   // 5 x B*H fp32
#define OFF_R1    1839104                  // 128x256 fp32
#define OFF_R2    1970176                  // 128x128 fp32
#define OFF_Y1    2035712                  // 5 x 128x256 fp32

typedef __attribute__((ext_vector_type(8))) short short8;
typedef __attribute__((ext_vector_type(4))) float f32x4;
typedef __attribute__((ext_vector_type(4))) int   i32x4a;

__device__ __forceinline__ unsigned short f2bf(float f) {
    union { float f; unsigned u; } v; v.f = f;
    unsigned r = v.u + 0x7fffu + ((v.u >> 16) & 1u);
    return (unsigned short)(r >> 16);
}

// overflow-safe fast tanh: t = exp(-2|x|) in (0,1]; tanh = sign(x)*(1-t)/(1+t)
__device__ __forceinline__ float ftanh(float x) {
    float ax = fabsf(x);
    float t  = __expf(-2.f * ax);
    float r  = (1.f - t) / (1.f + t);
    return copysignf(r, x);
}
__device__ __forceinline__ float fsig(float x) {
    return 1.f / (1.f + __expf(-x));
}

// 4 coalescing LLC-direct 16B loads (one per h k-block), pipelined, one drain.
#define HL4(R, a)                                                      \
  asm volatile(                                                        \
    "global_load_dwordx4 %0, %4, off sc0 sc1\n\t"                      \
    "global_load_dwordx4 %1, %4, off offset:1024 sc0 sc1\n\t"          \
    "global_load_dwordx4 %2, %4, off offset:2048 sc0 sc1\n\t"          \
    "global_load_dwordx4 %3, %4, off offset:3072 sc0 sc1\n\t"          \
    "s_waitcnt vmcnt(0)"                                               \
    : "=v"(R[0]), "=v"(R[1]), "=v"(R[2]), "=v"(R[3])                   \
    : "v"(a) : "memory")

__global__ __launch_bounds__(256, 1) void mclstm_main(
    const float* __restrict__ xin, const float* __restrict__ Wm,
    const float* __restrict__ Um,  const float* __restrict__ k1,
    const float* __restrict__ bias, const float* __restrict__ bias1,
    float* __restrict__ out, unsigned char* __restrict__ ws)
{
    __shared__ __align__(16) float pred[4][5][16][20]; // 25.6 KB K-split partials

    const int tid   = threadIdx.x;
    const int bid   = blockIdx.x;
    const int g_id  = bid & 7;        // batch-row group
    const int w_id  = bid >> 3;       // hidden-unit block [0,32)
    const int lane  = tid & 63;
    const int wv    = tid >> 6;
    const int j0    = w_id * 16;
    const int col16 = lane & 15;
    const int quad  = lane >> 4;

    unsigned* flg  = (unsigned*)(ws + OFF_ARR) + g_id * 32;
    float*    hfin = (float*)(ws + OFF_HFIN);
    float*    cfin = (float*)(ws + OFF_CFIN);

    // ---- B-fragments in REGISTERS (constant across all steps) ----
    // Bf[0][nt]   : x k-block (waves 0,1 only; wave wv owns k in [wv*32, wv*32+32))
    // Bf[1+i][nt] : h k-block i (wave's 4 blocks: k = (wv*4+i)*32 ... +32)
    // lane (col16, quad) holds B[n=col16][k = kbase + quad*8 + j], j=0..7
    short8 Bf[5][5];
#pragma unroll
    for (int i = 0; i < 4; ++i) {
        int kb = (wv * 4 + i) * 32 + quad * 8;     // row in U
#pragma unroll
        for (int nt = 0; nt < 5; ++nt) {
            int col = (nt < 4) ? (nt * Hh + j0 + col16)
                               : ((col16 < 5) ? (4 * Hh + col16) : -1);
            short8 b;
#pragma unroll
            for (int j = 0; j < 8; ++j) {
                float v = (col >= 0) ? Um[(size_t)(kb + j) * NGc + col] : 0.f;
                b[j] = (short)f2bf(v);
            }
            Bf[1 + i][nt] = b;
        }
    }
    if (wv < 2) {
        int kb = wv * 32 + quad * 8;               // row in W
#pragma unroll
        for (int nt = 0; nt < 5; ++nt) {
            int col = (nt < 4) ? (nt * Hh + j0 + col16)
                               : ((col16 < 5) ? (4 * Hh + col16) : -1);
            short8 b;
#pragma unroll
            for (int j = 0; j < 8; ++j) {
                float v = (col >= 0) ? Wm[(size_t)(kb + j) * NGc + col] : 0.f;
                b[j] = (short)f2bf(v);
            }
            Bf[0][nt] = b;
        }
    }

    // ---- per-thread cell constants: thread owns (row=tid>>4, unit=tid&15) ----
    const int rrow = tid >> 4, uu = tid & 15;
    const int u_g  = j0 + uu;
    const float bi = bias[0 * Hh + u_g], bf = bias[1 * Hh + u_g];
    const float bg = bias[2 * Hh + u_g], bo = bias[3 * Hh + u_g];
    float bd[5], kv[5];
#pragma unroll
    for (int c = 0; c < 5; ++c) { bd[c] = bias[4 * Hh + c]; kv[c] = k1[c * Hh + u_g]; }
    const float s1v = bias1[u_g], s2v = bias1[Hh + u_g];
    float cpreg = 0.f;

    // publish address for this thread's h element (tile order, 2B)
    unsigned long long pub_off = (unsigned long long)
        ((w_id >> 1) * 1024 + ((w_id & 1) * 2 + (uu >> 3)) * 256 + rrow * 16 + (uu & 7) * 2);

    __syncthreads();

    for (int t = 0; t < Ss; ++t) {
        char* hcur = (char*)ws + OFF_HB + (((t & 1) * 8 + g_id) * 16384);
        char* hnxt = (char*)ws + OFF_HB + ((((t + 1) & 1) * 8 + g_id) * 16384);

        f32x4 acc[5];
#pragma unroll
        for (int nt = 0; nt < 5; ++nt) { f32x4 z = {0.f, 0.f, 0.f, 0.f}; acc[nt] = z; }

        // ---- waves 0,1: own one x k-block; load + MFMA BEFORE poll ----
        if (wv < 2) {
            short8 Ax;
            const float* p = xin + ((size_t)(16 * g_id + col16) * Ss + t) * Ff
                           + wv * 32 + quad * 8;
            f32x4 f0 = *(const f32x4*)(p);
            f32x4 f1 = *(const f32x4*)(p + 4);
#pragma unroll
            for (int j = 0; j < 4; ++j) {
                Ax[j]     = (short)f2bf(f0[j]);
                Ax[4 + j] = (short)f2bf(f1[j]);
            }
#pragma unroll
            for (int nt = 0; nt < 5; ++nt)
                acc[nt] = __builtin_amdgcn_mfma_f32_16x16x32_bf16(Ax, Bf[0][nt], acc[nt], 0, 0, 0);
        }

        // ---- per-wave poll (2x unrolled pipelined loads halve detect lag) ----
        {
            unsigned* fp = flg + wv * 8 + (lane & 7);
            const bool mine = lane < 8;
            const unsigned tgt = (unsigned)t;
            for (;;) {
                unsigned v1 = mine ? __hip_atomic_load(fp, __ATOMIC_RELAXED,
                                                       __HIP_MEMORY_SCOPE_AGENT)
                                   : 0xFFFFFFFFu;
                unsigned v2 = mine ? __hip_atomic_load(fp, __ATOMIC_RELAXED,
                                                       __HIP_MEMORY_SCOPE_AGENT)
                                   : 0xFFFFFFFFu;
                if (__all((int)(v1 >= tgt)) || __all((int)(v2 >= tgt))) break;
            }
        }

        // ---- this wave's 4 h k-blocks: coalesced LLC-direct tile loads ----
        i32x4a Rh[4];
        {
            unsigned long long hb = (unsigned long long)
                (hcur + (wv * 4) * 1024 + quad * 256 + col16 * 16);
            HL4(Rh, hb);
        }

#pragma unroll
        for (int i = 0; i < 4; ++i) {
            short8 a = __builtin_bit_cast(short8, Rh[i]);
#pragma unroll
            for (int nt = 0; nt < 5; ++nt)
                acc[nt] = __builtin_amdgcn_mfma_f32_16x16x32_bf16(a, Bf[1 + i][nt], acc[nt], 0, 0, 0);
        }

        // ---- write K-split partials: one ds_write_b128 per nt ----
#pragma unroll
        for (int nt = 0; nt < 5; ++nt)
            *(f32x4*)&pred[wv][nt][col16][quad * 4] = acc[nt];
        __syncthreads();

        // ---- reduce + cell update + direct register->LLC publish ----
        {
            float gi = bi, gf = bf, gg = bg, go = bo;
            float dv[5];
#pragma unroll
            for (int c = 0; c < 5; ++c) dv[c] = bd[c];
#pragma unroll
            for (int w = 0; w < 4; ++w) {
                gi += pred[w][0][uu][rrow];
                gf += pred[w][1][uu][rrow];
                gg += pred[w][2][uu][rrow];
                go += pred[w][3][uu][rrow];
#pragma unroll
                for (int c = 0; c < 5; ++c) dv[c] += pred[w][4][c][rrow];
            }
            // softmax(tanh(.)): tanh in [-1,1] -> no max-subtraction needed
            float sden = 0.f;
#pragma unroll
            for (int c = 0; c < 5; ++c) { dv[c] = __expf(ftanh(dv[c])); sden += dv[c]; }
            float inv = 1.f / sden;
#pragma unroll
            for (int c = 0; c < 5; ++c) dv[c] *= inv;

            float i_ = fsig(gi);
            float f_ = fsig(gf);
            float g_ = ftanh(gg);
            float o_ = fsig(go);
            float c1v = ftanh(g_);
            float c5v = cpreg;
            float c3v = f_ * c5v + i_ * g_;
            float c2v = s2v * c3v + (1.f - s2v) * c1v;
            float c4v = s1v * c3v + (1.f - s1v) * c5v;
            float cn = dv[0] * kv[0] * c1v + dv[1] * kv[1] * c2v + dv[2] * kv[2] * c3v
                     + dv[3] * kv[3] * c4v + dv[4] * kv[4] * c5v;
            float hn = o_ * ftanh(cn);
            cpreg = cn;

            if (t < Ss - 1) {
                unsigned long long dst = (unsigned long long)hnxt + pub_off;
                unsigned bits = (unsigned)f2bf(hn);
                asm volatile("global_store_short %0, %1, off sc0 sc1\n\t"
                             "s_waitcnt vmcnt(0)"
                             :: "v"(dst), "v"(bits) : "memory");
            } else {
                size_t off = (size_t)(16 * g_id + rrow) * Hh + u_g;
                hfin[off] = hn;
                cfin[0 * Bb * Hh + off] = c1v;
                cfin[1 * Bb * Hh + off] = c2v;
                cfin[2 * Bb * Hh + off] = c3v;
                cfin[3 * Bb * Hh + off] = c4v;
                cfin[4 * Bb * Hh + off] = c5v;
                if (w_id == 0 && uu == 0) {
#pragma unroll
                    for (int c = 0; c < 5; ++c)
                        out[1408 + (16 * g_id + rrow) * 5 + c] = dv[c];
                }
            }
        }
        __syncthreads();                 // all 4 waves' h stores drained

        if (t < Ss - 1 && tid == 0)
            __hip_atomic_store(&flg[w_id], (unsigned)(t + 1),
                               __ATOMIC_RELAXED, __HIP_MEMORY_SCOPE_AGENT);
    }
}

// ---- heads: stage A: r1 = relu(h@rw1+rb1); y1[hd] = relu(c_hd@dw1+db1) ----
__global__ __launch_bounds__(256) void stageA(const unsigned char* __restrict__ ws,
    const float* __restrict__ rw1, const float* __restrict__ rb1,
    const float* __restrict__ dw1, const float* __restrict__ db1)
{
    __shared__ float sW[512 * 17];
    const int tid = threadIdx.x;
    const int blk = blockIdx.x;
    const float* hfin = (const float*)(ws + OFF_HFIN);
    const float* cfin = (const float*)(ws + OFF_CFIN);
    float* r1 = (float*)(ws + OFF_R1);
    float* y1 = (float*)(ws + OFF_Y1);

    const float* src; const float* Wm; const float* bv; float* dst; int cblk;
    if (blk < 16) { src = hfin; Wm = rw1; bv = rb1; dst = r1; cblk = blk; }
    else {
        int hd = (blk - 16) >> 4; cblk = (blk - 16) & 15;
        src = cfin + (size_t)hd * Bb * Hh; Wm = dw1; bv = db1;
        dst = y1 + (size_t)hd * Bb * 256;
    }
    for (int e = tid; e < 512 * 16; e += 256) {
        int k = e >> 4, c = e & 15;
        sW[k * 17 + c] = Wm[(size_t)k * 256 + cblk * 16 + c];
    }
    __syncthreads();
    for (int e = tid; e < 128 * 16; e += 256) {
        int r = e >> 4, c = e & 15;
        float a = bv[cblk * 16 + c];
        const float* sp = src + (size_t)r * 512;
        for (int k = 0; k < 512; k += 4) {
            f32x4 h4 = *(const f32x4*)(sp + k);
            a += h4[0] * sW[(k + 0) * 17 + c] + h4[1] * sW[(k + 1) * 17 + c]
               + h4[2] * sW[(k + 2) * 17 + c] + h4[3] * sW[(k + 3) * 17 + c];
        }
        dst[(size_t)r * 256 + cblk * 16 + c] = fmaxf(a, 0.f);
    }
}

// ---- stage B: r2 = relu(r1@rw2+rb2) ----
__global__ __launch_bounds__(256) void stageB(const unsigned char* __restrict__ ws,
    const float* __restrict__ rw2, const float* __restrict__ rb2)
{
    __shared__ float sW[256 * 17];
    const int tid = threadIdx.x;
    const int cblk = blockIdx.x;
    const float* r1 = (const float*)(ws + OFF_R1);
    float* r2 = (float*)(ws + OFF_R2);
    for (int e = tid; e < 256 * 16; e += 256) {
        int k = e >> 4, c = e & 15;
        sW[k * 17 + c] = rw2[(size_t)k * 128 + cblk * 16 + c];
    }
    __syncthreads();
    for (int e = tid; e < 128 * 16; e += 256) {
        int r = e >> 4, c = e & 15;
        float a = rb2[cblk * 16 + c];
        const float* sp = r1 + (size_t)r * 256;
        for (int k = 0; k < 256; k += 4) {
            f32x4 h4 = *(const f32x4*)(sp + k);
            a += h4[0] * sW[(k + 0) * 17 + c] + h4[1] * sW[(k + 1) * 17 + c]
               + h4[2] * sW[(k + 2) * 17 + c] + h4[3] * sW[(k + 3) * 17 + c];
        }
        r2[(size_t)r * 128 + cblk * 16 + c] = fmaxf(a, 0.f);
    }
}

// ---- stage C: BN + final projections + log_softmax ----
__global__ __launch_bounds__(256) void stageC(const unsigned char* __restrict__ ws,
    const float* __restrict__ rbng, const float* __restrict__ rbnb,
    const float* __restrict__ rw3,  const float* __restrict__ rb3,
    const float* __restrict__ dbng, const float* __restrict__ dbnb,
    const float* __restrict__ dw2,  const float* __restrict__ db2,
    float* __restrict__ out)
{
    __shared__ float sc[256], sh[256];
    const int tid = threadIdx.x;
    const int blk = blockIdx.x;
    const float* r2 = (const float*)(ws + OFF_R2);
    const float* y1 = (const float*)(ws + OFF_Y1);
    if (blk == 0) {
        if (tid < 128) {
            int c = tid; float s = 0.f, s2 = 0.f;
            for (int r = 0; r < 128; ++r) { float x = r2[r * 128 + c]; s += x; s2 += x * x; }
            float m = s * (1.f / 128.f), v = s2 * (1.f / 128.f) - m * m;
            float sca = rbng[c] * rsqrtf(v + 1e-5f);
            sc[c] = sca; sh[c] = rbnb[c] - m * sca;
        }
        __syncthreads();
        if (tid < 128) {
            int r = tid; float a = rb3[0];
            for (int c = 0; c < 128; ++c)
                a += (r2[r * 128 + c] * sc[c] + sh[c]) * rw3[c];
            out[r] = a;
        }
    } else {
        int hd = blk - 1;
        const float* y = y1 + (size_t)hd * 128 * 256;
        {
            int c = tid; float s = 0.f, s2 = 0.f;
            for (int r = 0; r < 128; ++r) { float x = y[r * 256 + c]; s += x; s2 += x * x; }
            float m = s * (1.f / 128.f), v = s2 * (1.f / 128.f) - m * m;
            float sca = dbng[c] * rsqrtf(v + 1e-5f);
            sc[c] = sca; sh[c] = dbnb[c] - m * sca;
        }
        __syncthreads();
        if (tid < 128) {
            int r = tid;
            float z0 = db2[0], z1 = db2[1];
            for (int c = 0; c < 256; ++c) {
                float yn = y[r * 256 + c] * sc[c] + sh[c];
                z0 += yn * dw2[c * 2 + 0];
                z1 += yn * dw2[c * 2 + 1];
            }
            float mx = fmaxf(z0, z1);
            float ls = mx + logf(__expf(z0 - mx) + __expf(z1 - mx));
            out[128 + hd * 256 + r * 2 + 0] = z0 - ls;
            out[128 + hd * 256 + r * 2 + 1] = z1 - ls;
        }
    }
}

extern "C" void kernel_launch(void* const* d_in, const int* in_sizes, int n_in,
                              void* d_out, int out_size, void* d_ws, size_t ws_size,
                              hipStream_t stream) {
    const float* x    = (const float*)d_in[0];
    const float* Wm   = (const float*)d_in[1];
    const float* Um   = (const float*)d_in[2];
    const float* k1   = (const float*)d_in[3];
    const float* bias = (const float*)d_in[4];
    const float* b1   = (const float*)d_in[5];
    const float* rw1  = (const float*)d_in[6];
    const float* rb1  = (const float*)d_in[7];
    const float* rw2  = (const float*)d_in[8];
    const float* rb2  = (const float*)d_in[9];
    const float* rbng = (const float*)d_in[10];
    const float* rbnb = (const float*)d_in[11];
    const float* rw3  = (const float*)d_in[12];
    const float* rb3  = (const float*)d_in[13];
    const float* dw1  = (const float*)d_in[14];
    const float* db1  = (const float*)d_in[15];
    const float* dbng = (const float*)d_in[16];
    const float* dbnb = (const float*)d_in[17];
    const float* dw2  = (const float*)d_in[18];
    const float* db2  = (const float*)d_in[19];
    (void)in_sizes; (void)n_in; (void)out_size; (void)ws_size;

    // zero flags + both h tile parities
    hipMemsetAsync(d_ws, 0, OFF_HFIN, stream);

    mclstm_main<<<256, 256, 0, stream>>>(x, Wm, Um, k1, bias, b1,
                                         (float*)d_out, (unsigned char*)d_ws);
    stageA<<<96, 256, 0, stream>>>((const unsigned char*)d_ws, rw1, rb1, dw1, db1);
    stageB<<<8, 256, 0, stream>>>((const unsigned char*)d_ws, rw2, rb2);
    stageC<<<6, 256, 0, stream>>>((const unsigned char*)d_ws, rbng, rbnb, rw3, rb3,
                                  dbng, dbnb, dw2, db2, (float*)d_out);
}

// Round 10
// 1673.375 us; speedup vs baseline: 4.4229x; 1.0610x over previous
//
#include <hip/hip_runtime.h>
#include <hip/hip_bf16.h>
#include <math.h>

#define Bb   128
#define Ss   512
#define Ff   64
#define Hh   512
#define NGc  2053          // 4*H + 5
#define Kk   576           // F + H

// workspace layout (bytes)
#define OFF_HB    4096                     // 2 parities x 8 groups x 32768 B tagged h tiles
#define OFF_HFIN  528384                   // B*H fp32
#define OFF_CFIN  790528                   // 5 x B*H fp32
#define OFF_R1    2101248                  // 128x256 fp32
#define OFF_R2    2232320                  // 128x128 fp32
#define OFF_Y1    2297856                  // 5 x 128x256 fp32

typedef __attribute__((ext_vector_type(8))) short short8;
typedef __attribute__((ext_vector_type(4))) float f32x4;
typedef __attribute__((ext_vector_type(4))) int   i32x4a;

__device__ __forceinline__ unsigned short f2bf(float f) {
    union { float f; unsigned u; } v; v.f = f;
    unsigned r = v.u + 0x7fffu + ((v.u >> 16) & 1u);
    return (unsigned short)(r >> 16);
}

// overflow-safe fast tanh: t = exp(-2|x|) in (0,1]; tanh = sign(x)*(1-t)/(1+t)
__device__ __forceinline__ float ftanh(float x) {
    float ax = fabsf(x);
    float t  = __expf(-2.f * ax);
    float r  = (1.f - t) / (1.f + t);
    return copysignf(r, x);
}
__device__ __forceinline__ float fsig(float x) {
    return 1.f / (1.f + __expf(-x));
}

// 8 coalescing LLC-direct 16B loads covering this wave's 4 tagged h k-blocks.
// Two base regs: %8 = hb, %9 = hb + 4096 (13-bit signed imm caps at 4095).
#define HL8(T, a, a2)                                                  \
  asm volatile(                                                        \
    "global_load_dwordx4 %0, %8, off sc0 sc1\n\t"                      \
    "global_load_dwordx4 %1, %8, off offset:16 sc0 sc1\n\t"            \
    "global_load_dwordx4 %2, %8, off offset:2048 sc0 sc1\n\t"          \
    "global_load_dwordx4 %3, %8, off offset:2064 sc0 sc1\n\t"          \
    "global_load_dwordx4 %4, %9, off sc0 sc1\n\t"                      \
    "global_load_dwordx4 %5, %9, off offset:16 sc0 sc1\n\t"            \
    "global_load_dwordx4 %6, %9, off offset:2048 sc0 sc1\n\t"          \
    "global_load_dwordx4 %7, %9, off offset:2064 sc0 sc1\n\t"          \
    "s_waitcnt vmcnt(0)"                                               \
    : "=v"(T[0]), "=v"(T[1]), "=v"(T[2]), "=v"(T[3]),                  \
      "=v"(T[4]), "=v"(T[5]), "=v"(T[6]), "=v"(T[7])                   \
    : "v"(a), "v"(a2) : "memory")

__global__ __launch_bounds__(256, 1) void mclstm_main(
    const float* __restrict__ xin, const float* __restrict__ Wm,
    const float* __restrict__ Um,  const float* __restrict__ k1,
    const float* __restrict__ bias, const float* __restrict__ bias1,
    float* __restrict__ out, unsigned char* __restrict__ ws)
{
    __shared__ __align__(16) float pred[2][4][5][16][20]; // 51.2 KB, step-parity dbuf

    const int tid   = threadIdx.x;
    const int bid   = blockIdx.x;
    const int g_id  = bid & 7;        // batch-row group
    const int w_id  = bid >> 3;       // hidden-unit block [0,32)
    const int lane  = tid & 63;
    const int wv    = tid >> 6;
    const int j0    = w_id * 16;
    const int col16 = lane & 15;
    const int quad  = lane >> 4;

    float* hfin = (float*)(ws + OFF_HFIN);
    float* cfin = (float*)(ws + OFF_CFIN);

    // ---- B-fragments in REGISTERS (constant across all steps) ----
    short8 Bf[5][5];
#pragma unroll
    for (int i = 0; i < 4; ++i) {
        int kb = (wv * 4 + i) * 32 + quad * 8;     // row in U
#pragma unroll
        for (int nt = 0; nt < 5; ++nt) {
            int col = (nt < 4) ? (nt * Hh + j0 + col16)
                               : ((col16 < 5) ? (4 * Hh + col16) : -1);
            short8 b;
#pragma unroll
            for (int j = 0; j < 8; ++j) {
                float v = (col >= 0) ? Um[(size_t)(kb + j) * NGc + col] : 0.f;
                b[j] = (short)f2bf(v);
            }
            Bf[1 + i][nt] = b;
        }
    }
    if (wv < 2) {
        int kb = wv * 32 + quad * 8;               // row in W
#pragma unroll
        for (int nt = 0; nt < 5; ++nt) {
            int col = (nt < 4) ? (nt * Hh + j0 + col16)
                               : ((col16 < 5) ? (4 * Hh + col16) : -1);
            short8 b;
#pragma unroll
            for (int j = 0; j < 8; ++j) {
                float v = (col >= 0) ? Wm[(size_t)(kb + j) * NGc + col] : 0.f;
                b[j] = (short)f2bf(v);
            }
            Bf[0][nt] = b;
        }
    }

    // ---- per-thread cell constants: thread owns (row=tid>>4, unit=tid&15) ----
    const int rrow = tid >> 4, uu = tid & 15;
    const int u_g  = j0 + uu;
    const float bi = bias[0 * Hh + u_g], bf = bias[1 * Hh + u_g];
    const float bg = bias[2 * Hh + u_g], bo = bias[3 * Hh + u_g];
    float bd[5], kv[5];
#pragma unroll
    for (int c = 0; c < 5; ++c) { bd[c] = bias[4 * Hh + c]; kv[c] = k1[c * Hh + u_g]; }
    const float s1v = bias1[u_g], s2v = bias1[Hh + u_g];
    float cpreg = 0.f;

    // publish offset: unit u_g is k-index; tile layout [kb 2048B][quad 512B][row 32B][jj 4B]
    const int kb_p = u_g >> 5, kin = u_g & 31;
    const unsigned pub_off = (unsigned)(kb_p * 2048 + (kin >> 3) * 512 + rrow * 32 + (kin & 7) * 4);

    __syncthreads();

    for (int t = 0; t < Ss; ++t) {
        char* hcur = (char*)ws + OFF_HB + (((t & 1) * 8 + g_id) * 32768);
        char* hnxt = (char*)ws + OFF_HB + ((((t + 1) & 1) * 8 + g_id) * 32768);
        const int pp = t & 1;

        f32x4 acc[5];
#pragma unroll
        for (int nt = 0; nt < 5; ++nt) { f32x4 z = {0.f, 0.f, 0.f, 0.f}; acc[nt] = z; }

        // ---- waves 0,1: own one x k-block; load + MFMA BEFORE poll ----
        if (wv < 2) {
            short8 Ax;
            const float* p = xin + ((size_t)(16 * g_id + col16) * Ss + t) * Ff
                           + wv * 32 + quad * 8;
            f32x4 f0 = *(const f32x4*)(p);
            f32x4 f1 = *(const f32x4*)(p + 4);
#pragma unroll
            for (int j = 0; j < 4; ++j) {
                Ax[j]     = (short)f2bf(f0[j]);
                Ax[4 + j] = (short)f2bf(f1[j]);
            }
#pragma unroll
            for (int nt = 0; nt < 5; ++nt)
                acc[nt] = __builtin_amdgcn_mfma_f32_16x16x32_bf16(Ax, Bf[0][nt], acc[nt], 0, 0, 0);
        }

        // ---- tagged poll+load fused: retry this wave's 8 tile loads until all
        // ---- 32 tags == t (one LLC round trip; no flags, no producer drain) ----
        i32x4a T[8];
        {
            unsigned long long hb = (unsigned long long)
                (hcur + (wv * 4) * 2048 + quad * 512 + col16 * 32);
            unsigned long long hb2 = hb + 4096;
            const unsigned tgt = (unsigned)t;
            for (int it = 0; it < (1 << 22); ++it) {
                HL8(T, hb, hb2);
                unsigned ok = 1u;
#pragma unroll
                for (int i = 0; i < 8; ++i)
#pragma unroll
                    for (int j = 0; j < 4; ++j)
                        ok &= (((unsigned)T[i][j] >> 16) == tgt) ? 1u : 0u;
                if (__all((int)ok)) break;
            }
        }

        // ---- repack tagged dwords -> bf16 A-frags, MFMA ----
#pragma unroll
        for (int i = 0; i < 4; ++i) {
            short8 a;
#pragma unroll
            for (int j = 0; j < 4; ++j) {
                a[j]     = (short)(T[2 * i][j] & 0xFFFF);
                a[4 + j] = (short)(T[2 * i + 1][j] & 0xFFFF);
            }
#pragma unroll
            for (int nt = 0; nt < 5; ++nt)
                acc[nt] = __builtin_amdgcn_mfma_f32_16x16x32_bf16(a, Bf[1 + i][nt], acc[nt], 0, 0, 0);
        }

        // ---- write K-split partials (parity-buffered) ----
#pragma unroll
        for (int nt = 0; nt < 5; ++nt)
            *(f32x4*)&pred[pp][wv][nt][col16][quad * 4] = acc[nt];
        __syncthreads();                  // the ONLY barrier per step

        // ---- reduce + cell update + tagged register->LLC publish ----
        {
            float gi = bi, gf = bf, gg = bg, go = bo;
            float dv[5];
#pragma unroll
            for (int c = 0; c < 5; ++c) dv[c] = bd[c];
#pragma unroll
            for (int w = 0; w < 4; ++w) {
                gi += pred[pp][w][0][uu][rrow];
                gf += pred[pp][w][1][uu][rrow];
                gg += pred[pp][w][2][uu][rrow];
                go += pred[pp][w][3][uu][rrow];
#pragma unroll
                for (int c = 0; c < 5; ++c) dv[c] += pred[pp][w][4][c][rrow];
            }
            // softmax(tanh(.)): tanh in [-1,1] -> no max-subtraction needed
            float sden = 0.f;
#pragma unroll
            for (int c = 0; c < 5; ++c) { dv[c] = __expf(ftanh(dv[c])); sden += dv[c]; }
            float inv = 1.f / sden;
#pragma unroll
            for (int c = 0; c < 5; ++c) dv[c] *= inv;

            float i_ = fsig(gi);
            float f_ = fsig(gf);
            float g_ = ftanh(gg);
            float o_ = fsig(go);
            float c1v = ftanh(g_);
            float c5v = cpreg;
            float c3v = f_ * c5v + i_ * g_;
            float c2v = s2v * c3v + (1.f - s2v) * c1v;
            float c4v = s1v * c3v + (1.f - s1v) * c5v;
            float cn = dv[0] * kv[0] * c1v + dv[1] * kv[1] * c2v + dv[2] * kv[2] * c3v
                     + dv[3] * kv[3] * c4v + dv[4] * kv[4] * c5v;
            float hn = o_ * ftanh(cn);
            cpreg = cn;

            if (t < Ss - 1) {
                unsigned word = ((unsigned)(t + 1) << 16) | (unsigned)f2bf(hn);
                __hip_atomic_store((unsigned*)(hnxt + pub_off), word,
                                   __ATOMIC_RELAXED, __HIP_MEMORY_SCOPE_AGENT);
            } else {
                size_t off = (size_t)(16 * g_id + rrow) * Hh + u_g;
                hfin[off] = hn;
                cfin[0 * Bb * Hh + off] = c1v;
                cfin[1 * Bb * Hh + off] = c2v;
                cfin[2 * Bb * Hh + off] = c3v;
                cfin[3 * Bb * Hh + off] = c4v;
                cfin[4 * Bb * Hh + off] = c5v;
                if (w_id == 0 && uu == 0) {
#pragma unroll
                    for (int c = 0; c < 5; ++c)
                        out[1408 + (16 * g_id + rrow) * 5 + c] = dv[c];
                }
            }
        }
        // no end-of-step barrier: pred is parity-buffered; the next step's
        // shared barrier orders read(t) before write(t+2).
    }
}

// ---- heads: stage A: r1 = relu(h@rw1+rb1); y1[hd] = relu(c_hd@dw1+db1) ----
__global__ __launch_bounds__(256) void stageA(const unsigned char* __restrict__ ws,
    const float* __restrict__ rw1, const float* __restrict__ rb1,
    const float* __restrict__ dw1, const float* __restrict__ db1)
{
    __shared__ float sW[512 * 17];
    const int tid = threadIdx.x;
    const int blk = blockIdx.x;
    const float* hfin = (const float*)(ws + OFF_HFIN);
    const float* cfin = (const float*)(ws + OFF_CFIN);
    float* r1 = (float*)(ws + OFF_R1);
    float* y1 = (float*)(ws + OFF_Y1);

    const float* src; const float* Wm; const float* bv; float* dst; int cblk;
    if (blk < 16) { src = hfin; Wm = rw1; bv = rb1; dst = r1; cblk = blk; }
    else {
        int hd = (blk - 16) >> 4; cblk = (blk - 16) & 15;
        src = cfin + (size_t)hd * Bb * Hh; Wm = dw1; bv = db1;
        dst = y1 + (size_t)hd * Bb * 256;
    }
    for (int e = tid; e < 512 * 16; e += 256) {
        int k = e >> 4, c = e & 15;
        sW[k * 17 + c] = Wm[(size_t)k * 256 + cblk * 16 + c];
    }
    __syncthreads();
    for (int e = tid; e < 128 * 16; e += 256) {
        int r = e >> 4, c = e & 15;
        float a = bv[cblk * 16 + c];
        const float* sp = src + (size_t)r * 512;
        for (int k = 0; k < 512; k += 4) {
            f32x4 h4 = *(const f32x4*)(sp + k);
            a += h4[0] * sW[(k + 0) * 17 + c] + h4[1] * sW[(k + 1) * 17 + c]
               + h4[2] * sW[(k + 2) * 17 + c] + h4[3] * sW[(k + 3) * 17 + c];
        }
        dst[(size_t)r * 256 + cblk * 16 + c] = fmaxf(a, 0.f);
    }
}

// ---- stage B: r2 = relu(r1@rw2+rb2) ----
__global__ __launch_bounds__(256) void stageB(const unsigned char* __restrict__ ws,
    const float* __restrict__ rw2, const float* __restrict__ rb2)
{
    __shared__ float sW[256 * 17];
    const int tid = threadIdx.x;
    const int cblk = blockIdx.x;
    const float* r1 = (const float*)(ws + OFF_R1);
    float* r2 = (float*)(ws + OFF_R2);
    for (int e = tid; e < 256 * 16; e += 256) {
        int k = e >> 4, c = e & 15;
        sW[k * 17 + c] = rw2[(size_t)k * 128 + cblk * 16 + c];
    }
    __syncthreads();
    for (int e = tid; e < 128 * 16; e += 256) {
        int r = e >> 4, c = e & 15;
        float a = rb2[cblk * 16 + c];
        const float* sp = r1 + (size_t)r * 256;
        for (int k = 0; k < 256; k += 4) {
            f32x4 h4 = *(const f32x4*)(sp + k);
            a += h4[0] * sW[(k + 0) * 17 + c] + h4[1] * sW[(k + 1) * 17 + c]
               + h4[2] * sW[(k + 2) * 17 + c] + h4[3] * sW[(k + 3) * 17 + c];
        }
        r2[(size_t)r * 128 + cblk * 16 + c] = fmaxf(a, 0.f);
    }
}

// ---- stage C: BN + final projections + log_softmax ----
__global__ __launch_bounds__(256) void stageC(const unsigned char* __restrict__ ws,
    const float* __restrict__ rbng, const float* __restrict__ rbnb,
    const float* __restrict__ rw3,  const float* __restrict__ rb3,
    const float* __restrict__ dbng, const float* __restrict__ dbnb,
    const float* __restrict__ dw2,  const float* __restrict__ db2,
    float* __restrict__ out)
{
    __shared__ float sc[256], sh[256];
    const int tid = threadIdx.x;
    const int blk = blockIdx.x;
    const float* r2 = (const float*)(ws + OFF_R2);
    const float* y1 = (const float*)(ws + OFF_Y1);
    if (blk == 0) {
        if (tid < 128) {
            int c = tid; float s = 0.f, s2 = 0.f;
            for (int r = 0; r < 128; ++r) { float x = r2[r * 128 + c]; s += x; s2 += x * x; }
            float m = s * (1.f / 128.f), v = s2 * (1.f / 128.f) - m * m;
            float sca = rbng[c] * rsqrtf(v + 1e-5f);
            sc[c] = sca; sh[c] = rbnb[c] - m * sca;
        }
        __syncthreads();
        if (tid < 128) {
            int r = tid; float a = rb3[0];
            for (int c = 0; c < 128; ++c)
                a += (r2[r * 128 + c] * sc[c] + sh[c]) * rw3[c];
            out[r] = a;
        }
    } else {
        int hd = blk - 1;
        const float* y = y1 + (size_t)hd * 128 * 256;
        {
            int c = tid; float s = 0.f, s2 = 0.f;
            for (int r = 0; r < 128; ++r) { float x = y[r * 256 + c]; s += x; s2 += x * x; }
            float m = s * (1.f / 128.f), v = s2 * (1.f / 128.f) - m * m;
            float sca = dbng[c] * rsqrtf(v + 1e-5f);
            sc[c] = sca; sh[c] = dbnb[c] - m * sca;
        }
        __syncthreads();
        if (tid < 128) {
            int r = tid;
            float z0 = db2[0], z1 = db2[1];
            for (int c = 0; c < 256; ++c) {
                float yn = y[r * 256 + c] * sc[c] + sh[c];
                z0 += yn * dw2[c * 2 + 0];
                z1 += yn * dw2[c * 2 + 1];
            }
            float mx = fmaxf(z0, z1);
            float ls = mx + logf(__expf(z0 - mx) + __expf(z1 - mx));
            out[128 + hd * 256 + r * 2 + 0] = z0 - ls;
            out[128 + hd * 256 + r * 2 + 1] = z1 - ls;
        }
    }
}

extern "C" void kernel_launch(void* const* d_in, const int* in_sizes, int n_in,
                              void* d_out, int out_size, void* d_ws, size_t ws_size,
                              hipStream_t stream) {
    const float* x    = (const float*)d_in[0];
    const float* Wm   = (const float*)d_in[1];
    const float* Um   = (const float*)d_in[2];
    const float* k1   = (const float*)d_in[3];
    const float* bias = (const float*)d_in[4];
    const float* b1   = (const float*)d_in[5];
    const float* rw1  = (const float*)d_in[6];
    const float* rb1  = (const float*)d_in[7];
    const float* rw2  = (const float*)d_in[8];
    const float* rb2  = (const float*)d_in[9];
    const float* rbng = (const float*)d_in[10];
    const float* rbnb = (const float*)d_in[11];
    const float* rw3  = (const float*)d_in[12];
    const float* rb3  = (const float*)d_in[13];
    const float* dw1  = (const float*)d_in[14];
    const float* db1  = (const float*)d_in[15];
    const float* dbng = (const float*)d_in[16];
    const float* dbnb = (const float*)d_in[17];
    const float* dw2  = (const float*)d_in[18];
    const float* db2  = (const float*)d_in[19];
    (void)in_sizes; (void)n_in; (void)out_size; (void)ws_size;

    // zero both tagged h tile parities (tag 0 == step 0, h0 = 0)
    hipMemsetAsync(d_ws, 0, OFF_HFIN, stream);

    mclstm_main<<<256, 256, 0, stream>>>(x, Wm, Um, k1, bias, b1,
                                         (float*)d_out, (unsigned char*)d_ws);
    stageA<<<96, 256, 0, stream>>>((const unsigned char*)d_ws, rw1, rb1, dw1, db1);
    stageB<<<8, 256, 0, stream>>>((const unsigned char*)d_ws, rw2, rb2);
    stageC<<<6, 256, 0, stream>>>((const unsigned char*)d_ws, rbng, rbnb, rw3, rb3,
                                  dbng, dbnb, dw2, db2, (float*)d_out);
}

// Round 11
// 1407.431 us; speedup vs baseline: 5.2586x; 1.1890x over previous
//
#include <hip/hip_runtime.h>
#include <hip/hip_bf16.h>
#include <math.h>

#define Bb   128
#define Ss   512
#define Ff   64
#define Hh   512
#define NGc  2053          // 4*H + 5
#define Kk   576           // F + H

// workspace layout (bytes)
#define OFF_HB    4096                     // 2 parities x 8 groups x 32768 B tagged h tiles
#define OFF_HFIN  528384                   // B*H fp32
#define OFF_CFIN  790528                   // 5 x B*H fp32
#define OFF_R1    2101248                  // 128x256 fp32
#define OFF_R2    2232320                  // 128x128 fp32
#define OFF_Y1    2297856                  // 5 x 128x256 fp32

typedef __attribute__((ext_vector_type(8))) short short8;
typedef __attribute__((ext_vector_type(4))) float f32x4;
typedef __attribute__((ext_vector_type(4))) int   i32x4a;

__device__ __forceinline__ unsigned short f2bf(float f) {
    union { float f; unsigned u; } v; v.f = f;
    unsigned r = v.u + 0x7fffu + ((v.u >> 16) & 1u);
    return (unsigned short)(r >> 16);
}

__device__ __forceinline__ float frcp(float x) { return __builtin_amdgcn_rcpf(x); }

// overflow-safe fast tanh via v_exp + v_rcp (no slow fp32 div sequence)
__device__ __forceinline__ float ftanh(float x) {
    float ax = fabsf(x);
    float t  = __expf(-2.f * ax);
    float r  = (1.f - t) * frcp(1.f + t);
    return copysignf(r, x);
}
__device__ __forceinline__ float fsig(float x) {
    return frcp(1.f + __expf(-x));
}

// 8 coalescing LLC-direct 16B loads covering this wave's 4 tagged h k-blocks.
// Two base regs: %8 = hb, %9 = hb + 4096 (13-bit signed imm caps at 4095).
#define HL8(T, a, a2)                                                  \
  asm volatile(                                                        \
    "global_load_dwordx4 %0, %8, off sc0 sc1\n\t"                      \
    "global_load_dwordx4 %1, %8, off offset:16 sc0 sc1\n\t"            \
    "global_load_dwordx4 %2, %8, off offset:2048 sc0 sc1\n\t"          \
    "global_load_dwordx4 %3, %8, off offset:2064 sc0 sc1\n\t"          \
    "global_load_dwordx4 %4, %9, off sc0 sc1\n\t"                      \
    "global_load_dwordx4 %5, %9, off offset:16 sc0 sc1\n\t"            \
    "global_load_dwordx4 %6, %9, off offset:2048 sc0 sc1\n\t"          \
    "global_load_dwordx4 %7, %9, off offset:2064 sc0 sc1\n\t"          \
    "s_waitcnt vmcnt(0)"                                               \
    : "=v"(T[0]), "=v"(T[1]), "=v"(T[2]), "=v"(T[3]),                  \
      "=v"(T[4]), "=v"(T[5]), "=v"(T[6]), "=v"(T[7])                   \
    : "v"(a), "v"(a2) : "memory")

__global__ __launch_bounds__(256, 1) void mclstm_main(
    const float* __restrict__ xin, const float* __restrict__ Wm,
    const float* __restrict__ Um,  const float* __restrict__ k1,
    const float* __restrict__ bias, const float* __restrict__ bias1,
    float* __restrict__ out, unsigned char* __restrict__ ws)
{
    // gate partials: [parity][wave][row][unit][{i,f,g,o}] -> 16B vector exchange
    __shared__ __align__(16) float predG[2][4][16][16][4];   // 32 KB
    // d partials:   [parity][c][row][wave] -> consumer reads one b128 per c
    __shared__ __align__(16) float predD[2][5][16][4];       // 2.5 KB

    const int tid   = threadIdx.x;
    const int bid   = blockIdx.x;
    const int g_id  = bid & 7;        // batch-row group
    const int w_id  = bid >> 3;       // hidden-unit block [0,32)
    const int lane  = tid & 63;
    const int wv    = tid >> 6;
    const int j0    = w_id * 16;
    const int col16 = lane & 15;
    const int quad  = lane >> 4;

    float* hfin = (float*)(ws + OFF_HFIN);
    float* cfin = (float*)(ws + OFF_CFIN);

    // ---- B-fragments in REGISTERS (constant across all steps) ----
    short8 Bf[5][5];
#pragma unroll
    for (int i = 0; i < 4; ++i) {
        int kb = (wv * 4 + i) * 32 + quad * 8;     // row in U
#pragma unroll
        for (int nt = 0; nt < 5; ++nt) {
            int col = (nt < 4) ? (nt * Hh + j0 + col16)
                               : ((col16 < 5) ? (4 * Hh + col16) : -1);
            short8 b;
#pragma unroll
            for (int j = 0; j < 8; ++j) {
                float v = (col >= 0) ? Um[(size_t)(kb + j) * NGc + col] : 0.f;
                b[j] = (short)f2bf(v);
            }
            Bf[1 + i][nt] = b;
        }
    }
    if (wv < 2) {
        int kb = wv * 32 + quad * 8;               // row in W
#pragma unroll
        for (int nt = 0; nt < 5; ++nt) {
            int col = (nt < 4) ? (nt * Hh + j0 + col16)
                               : ((col16 < 5) ? (4 * Hh + col16) : -1);
            short8 b;
#pragma unroll
            for (int j = 0; j < 8; ++j) {
                float v = (col >= 0) ? Wm[(size_t)(kb + j) * NGc + col] : 0.f;
                b[j] = (short)f2bf(v);
            }
            Bf[0][nt] = b;
        }
    }

    // ---- per-thread cell constants: thread owns (row=tid>>4, unit=tid&15) ----
    const int rrow = tid >> 4, uu = tid & 15;
    const int u_g  = j0 + uu;
    const float bi = bias[0 * Hh + u_g], bf = bias[1 * Hh + u_g];
    const float bg = bias[2 * Hh + u_g], bo = bias[3 * Hh + u_g];
    float bd[5], kv[5];
#pragma unroll
    for (int c = 0; c < 5; ++c) { bd[c] = bias[4 * Hh + c]; kv[c] = k1[c * Hh + u_g]; }
    const float s1v = bias1[u_g], s2v = bias1[Hh + u_g];
    float cpreg = 0.f;

    // publish offset: unit u_g is k-index; tile layout [kb 2048B][quad 512B][row 32B][jj 4B]
    const int kb_p = u_g >> 5, kin = u_g & 31;
    const unsigned pub_off = (unsigned)(kb_p * 2048 + (kin >> 3) * 512 + rrow * 32 + (kin & 7) * 4);

    __syncthreads();

    for (int t = 0; t < Ss; ++t) {
        char* hcur = (char*)ws + OFF_HB + (((t & 1) * 8 + g_id) * 32768);
        char* hnxt = (char*)ws + OFF_HB + ((((t + 1) & 1) * 8 + g_id) * 32768);
        const int pp = t & 1;

        f32x4 acc[5];
#pragma unroll
        for (int nt = 0; nt < 5; ++nt) { f32x4 z = {0.f, 0.f, 0.f, 0.f}; acc[nt] = z; }

        // ---- waves 0,1: own one x k-block; load + MFMA BEFORE poll ----
        if (wv < 2) {
            short8 Ax;
            const float* p = xin + ((size_t)(16 * g_id + col16) * Ss + t) * Ff
                           + wv * 32 + quad * 8;
            f32x4 f0 = *(const f32x4*)(p);
            f32x4 f1 = *(const f32x4*)(p + 4);
#pragma unroll
            for (int j = 0; j < 4; ++j) {
                Ax[j]     = (short)f2bf(f0[j]);
                Ax[4 + j] = (short)f2bf(f1[j]);
            }
#pragma unroll
            for (int nt = 0; nt < 5; ++nt)
                acc[nt] = __builtin_amdgcn_mfma_f32_16x16x32_bf16(Ax, Bf[0][nt], acc[nt], 0, 0, 0);
        }

        // ---- tagged poll+load fused: retry this wave's 8 tile loads until all
        // ---- 32 tags == t (XOR/OR-tree check; one LLC round trip; no flags) ----
        i32x4a T[8];
        {
            unsigned long long hb = (unsigned long long)
                (hcur + (wv * 4) * 2048 + quad * 512 + col16 * 32);
            unsigned long long hb2 = hb + 4096;
            const unsigned expect = (unsigned)t << 16;
            for (int it = 0; it < (1 << 22); ++it) {
                HL8(T, hb, hb2);
                unsigned diff = 0u;
#pragma unroll
                for (int i = 0; i < 8; ++i)
#pragma unroll
                    for (int j = 0; j < 4; ++j)
                        diff |= ((unsigned)T[i][j]) ^ expect;
                if (__all((int)((diff >> 16) == 0u))) break;
            }
        }

        // ---- repack tagged dwords -> bf16 A-frags, MFMA ----
#pragma unroll
        for (int i = 0; i < 4; ++i) {
            short8 a;
#pragma unroll
            for (int j = 0; j < 4; ++j) {
                a[j]     = (short)(T[2 * i][j] & 0xFFFF);
                a[4 + j] = (short)(T[2 * i + 1][j] & 0xFFFF);
            }
#pragma unroll
            for (int nt = 0; nt < 5; ++nt)
                acc[nt] = __builtin_amdgcn_mfma_f32_16x16x32_bf16(a, Bf[1 + i][nt], acc[nt], 0, 0, 0);
        }

        // ---- write K-split partials: gates as one f32x4 per (row,unit) ----
#pragma unroll
        for (int j = 0; j < 4; ++j) {
            f32x4 g4 = {acc[0][j], acc[1][j], acc[2][j], acc[3][j]};
            *(f32x4*)&predG[pp][wv][quad * 4 + j][col16][0] = g4;
        }
        if (col16 < 5) {
#pragma unroll
            for (int j = 0; j < 4; ++j)
                predD[pp][col16][quad * 4 + j][wv] = acc[4][j];
        }
        __syncthreads();                  // the ONLY barrier per step

        // ---- reduce + cell update + tagged register->LLC publish ----
        {
            f32x4 g4 = {bi, bf, bg, bo};
#pragma unroll
            for (int w = 0; w < 4; ++w) {
                f32x4 p = *(const f32x4*)&predG[pp][w][rrow][uu][0];
                g4 += p;
            }
            float dv[5];
#pragma unroll
            for (int c = 0; c < 5; ++c) {
                f32x4 dp = *(const f32x4*)&predD[pp][c][rrow][0];
                dv[c] = bd[c] + ((dp[0] + dp[1]) + (dp[2] + dp[3]));
            }
            // softmax(tanh(.)): tanh in [-1,1] -> no max-subtraction needed
            float sden = 0.f;
#pragma unroll
            for (int c = 0; c < 5; ++c) { dv[c] = __expf(ftanh(dv[c])); sden += dv[c]; }
            float inv = frcp(sden);
#pragma unroll
            for (int c = 0; c < 5; ++c) dv[c] *= inv;

            float i_ = fsig(g4[0]);
            float f_ = fsig(g4[1]);
            float g_ = ftanh(g4[2]);
            float o_ = fsig(g4[3]);
            float c1v = ftanh(g_);
            float c5v = cpreg;
            float c3v = f_ * c5v + i_ * g_;
            float c2v = s2v * c3v + (1.f - s2v) * c1v;
            float c4v = s1v * c3v + (1.f - s1v) * c5v;
            float cn = dv[0] * kv[0] * c1v + dv[1] * kv[1] * c2v + dv[2] * kv[2] * c3v
                     + dv[3] * kv[3] * c4v + dv[4] * kv[4] * c5v;
            float hn = o_ * ftanh(cn);
            cpreg = cn;

            if (t < Ss - 1) {
                unsigned word = ((unsigned)(t + 1) << 16) | (unsigned)f2bf(hn);
                __hip_atomic_store((unsigned*)(hnxt + pub_off), word,
                                   __ATOMIC_RELAXED, __HIP_MEMORY_SCOPE_AGENT);
            } else {
                size_t off = (size_t)(16 * g_id + rrow) * Hh + u_g;
                hfin[off] = hn;
                cfin[0 * Bb * Hh + off] = c1v;
                cfin[1 * Bb * Hh + off] = c2v;
                cfin[2 * Bb * Hh + off] = c3v;
                cfin[3 * Bb * Hh + off] = c4v;
                cfin[4 * Bb * Hh + off] = c5v;
                if (w_id == 0 && uu == 0) {
#pragma unroll
                    for (int c = 0; c < 5; ++c)
                        out[1408 + (16 * g_id + rrow) * 5 + c] = dv[c];
                }
            }
        }
        // no end-of-step barrier: pred is parity-buffered; the next step's
        // shared barrier orders read(t) before write(t+2).
    }
}

// ---- heads: stage A: r1 = relu(h@rw1+rb1); y1[hd] = relu(c_hd@dw1+db1) ----
__global__ __launch_bounds__(256) void stageA(const unsigned char* __restrict__ ws,
    const float* __restrict__ rw1, const float* __restrict__ rb1,
    const float* __restrict__ dw1, const float* __restrict__ db1)
{
    __shared__ float sW[512 * 17];
    const int tid = threadIdx.x;
    const int blk = blockIdx.x;
    const float* hfin = (const float*)(ws + OFF_HFIN);
    const float* cfin = (const float*)(ws + OFF_CFIN);
    float* r1 = (float*)(ws + OFF_R1);
    float* y1 = (float*)(ws + OFF_Y1);

    const float* src; const float* Wm; const float* bv; float* dst; int cblk;
    if (blk < 16) { src = hfin; Wm = rw1; bv = rb1; dst = r1; cblk = blk; }
    else {
        int hd = (blk - 16) >> 4; cblk = (blk - 16) & 15;
        src = cfin + (size_t)hd * Bb * Hh; Wm = dw1; bv = db1;
        dst = y1 + (size_t)hd * Bb * 256;
    }
    for (int e = tid; e < 512 * 16; e += 256) {
        int k = e >> 4, c = e & 15;
        sW[k * 17 + c] = Wm[(size_t)k * 256 + cblk * 16 + c];
    }
    __syncthreads();
    for (int e = tid; e < 128 * 16; e += 256) {
        int r = e >> 4, c = e & 15;
        float a = bv[cblk * 16 + c];
        const float* sp = src + (size_t)r * 512;
        for (int k = 0; k < 512; k += 4) {
            f32x4 h4 = *(const f32x4*)(sp + k);
            a += h4[0] * sW[(k + 0) * 17 + c] + h4[1] * sW[(k + 1) * 17 + c]
               + h4[2] * sW[(k + 2) * 17 + c] + h4[3] * sW[(k + 3) * 17 + c];
        }
        dst[(size_t)r * 256 + cblk * 16 + c] = fmaxf(a, 0.f);
    }
}

// ---- stage B: r2 = relu(r1@rw2+rb2) ----
__global__ __launch_bounds__(256) void stageB(const unsigned char* __restrict__ ws,
    const float* __restrict__ rw2, const float* __restrict__ rb2)
{
    __shared__ float sW[256 * 17];
    const int tid = threadIdx.x;
    const int cblk = blockIdx.x;
    const float* r1 = (const float*)(ws + OFF_R1);
    float* r2 = (float*)(ws + OFF_R2);
    for (int e = tid; e < 256 * 16; e += 256) {
        int k = e >> 4, c = e & 15;
        sW[k * 17 + c] = rw2[(size_t)k * 128 + cblk * 16 + c];
    }
    __syncthreads();
    for (int e = tid; e < 128 * 16; e += 256) {
        int r = e >> 4, c = e & 15;
        float a = rb2[cblk * 16 + c];
        const float* sp = r1 + (size_t)r * 256;
        for (int k = 0; k < 256; k += 4) {
            f32x4 h4 = *(const f32x4*)(sp + k);
            a += h4[0] * sW[(k + 0) * 17 + c] + h4[1] * sW[(k + 1) * 17 + c]
               + h4[2] * sW[(k + 2) * 17 + c] + h4[3] * sW[(k + 3) * 17 + c];
        }
        r2[(size_t)r * 128 + cblk * 16 + c] = fmaxf(a, 0.f);
    }
}

// ---- stage C: BN + final projections + log_softmax ----
__global__ __launch_bounds__(256) void stageC(const unsigned char* __restrict__ ws,
    const float* __restrict__ rbng, const float* __restrict__ rbnb,
    const float* __restrict__ rw3,  const float* __restrict__ rb3,
    const float* __restrict__ dbng, const float* __restrict__ dbnb,
    const float* __restrict__ dw2,  const float* __restrict__ db2,
    float* __restrict__ out)
{
    __shared__ float sc[256], sh[256];
    const int tid = threadIdx.x;
    const int blk = blockIdx.x;
    const float* r2 = (const float*)(ws + OFF_R2);
    const float* y1 = (const float*)(ws + OFF_Y1);
    if (blk == 0) {
        if (tid < 128) {
            int c = tid; float s = 0.f, s2 = 0.f;
            for (int r = 0; r < 128; ++r) { float x = r2[r * 128 + c]; s += x; s2 += x * x; }
            float m = s * (1.f / 128.f), v = s2 * (1.f / 128.f) - m * m;
            float sca = rbng[c] * rsqrtf(v + 1e-5f);
            sc[c] = sca; sh[c] = rbnb[c] - m * sca;
        }
        __syncthreads();
        if (tid < 128) {
            int r = tid; float a = rb3[0];
            for (int c = 0; c < 128; ++c)
                a += (r2[r * 128 + c] * sc[c] + sh[c]) * rw3[c];
            out[r] = a;
        }
    } else {
        int hd = blk - 1;
        const float* y = y1 + (size_t)hd * 128 * 256;
        {
            int c = tid; float s = 0.f, s2 = 0.f;
            for (int r = 0; r < 128; ++r) { float x = y[r * 256 + c]; s += x; s2 += x * x; }
            float m = s * (1.f / 128.f), v = s2 * (1.f / 128.f) - m * m;
            float sca = dbng[c] * rsqrtf(v + 1e-5f);
            sc[c] = sca; sh[c] = dbnb[c] - m * sca;
        }
        __syncthreads();
        if (tid < 128) {
            int r = tid;
            float z0 = db2[0], z1 = db2[1];
            for (int c = 0; c < 256; ++c) {
                float yn = y[r * 256 + c] * sc[c] + sh[c];
                z0 += yn * dw2[c * 2 + 0];
                z1 += yn * dw2[c * 2 + 1];
            }
            float mx = fmaxf(z0, z1);
            float ls = mx + logf(__expf(z0 - mx) + __expf(z1 - mx));
            out[128 + hd * 256 + r * 2 + 0] = z0 - ls;
            out[128 + hd * 256 + r * 2 + 1] = z1 - ls;
        }
    }
}

extern "C" void kernel_launch(void* const* d_in, const int* in_sizes, int n_in,
                              void* d_out, int out_size, void* d_ws, size_t ws_size,
                              hipStream_t stream) {
    const float* x    = (const float*)d_in[0];
    const float* Wm   = (const float*)d_in[1];
    const float* Um   = (const float*)d_in[2];
    const float* k1   = (const float*)d_in[3];
    const float* bias = (const float*)d_in[4];
    const float* b1   = (const float*)d_in[5];
    const float* rw1  = (const float*)d_in[6];
    const float* rb1  = (const float*)d_in[7];
    const float* rw2  = (const float*)d_in[8];
    const float* rb2  = (const float*)d_in[9];
    const float* rbng = (const float*)d_in[10];
    const float* rbnb = (const float*)d_in[11];
    const float* rw3  = (const float*)d_in[12];
    const float* rb3  = (const float*)d_in[13];
    const float* dw1  = (const float*)d_in[14];
    const float* db1  = (const float*)d_in[15];
    const float* dbng = (const float*)d_in[16];
    const float* dbnb = (const float*)d_in[17];
    const float* dw2  = (const float*)d_in[18];
    const float* db2  = (const float*)d_in[19];
    (void)in_sizes; (void)n_in; (void)out_size; (void)ws_size;

    // zero both tagged h tile parities (tag 0 == step 0, h0 = 0)
    hipMemsetAsync(d_ws, 0, OFF_HFIN, stream);

    mclstm_main<<<256, 256, 0, stream>>>(x, Wm, Um, k1, bias, b1,
                                         (float*)d_out, (unsigned char*)d_ws);
    stageA<<<96, 256, 0, stream>>>((const unsigned char*)d_ws, rw1, rb1, dw1, db1);
    stageB<<<8, 256, 0, stream>>>((const unsigned char*)d_ws, rw2, rb2);
    stageC<<<6, 256, 0, stream>>>((const unsigned char*)d_ws, rbng, rbnb, rw3, rb3,
                                  dbng, dbnb, dw2, db2, (float*)d_out);
}